// Round 7
// baseline (212.240 us; speedup 1.0000x reference)
//
#include <hip/hip_runtime.h>
#include <math.h>

#define B_   8
#define S_   1024
#define NXc  768
#define H_   12
#define HDc  64
#define M_   (B_*S_)        // 8192
#define NQKV (3*NXc)        // 2304

typedef __attribute__((ext_vector_type(8))) short short8;
typedef __attribute__((ext_vector_type(4))) float f32x4;

__device__ inline unsigned short f2bf(float f) {
  unsigned u = __float_as_uint(f);
  return (unsigned short)((u + 0x7fffu + ((u >> 16) & 1u)) >> 16);
}
__device__ inline float bf2f(unsigned short h) {
  return __uint_as_float(((unsigned)h) << 16);
}
__device__ inline void gl_lds16(const unsigned short* g, unsigned short* l) {
  __builtin_amdgcn_global_load_lds(
      (const __attribute__((address_space(1))) void*)g,
      (__attribute__((address_space(3))) void*)l, 16, 0, 0);
}

// ---- workspace layout (floats) ----
static const size_t UA_OFF_F  = 0;                                   // bf16 Ut attn [NQKV][NXc]
static const size_t UA_F_CNT  = ((size_t)NQKV * NXc + 1) / 2;        // 884736
static const size_t UP_OFF_F  = UA_OFF_F + UA_F_CNT;                 // bf16 Ut proj [NXc][NXc]
static const size_t UP_F_CNT  = ((size_t)NXc * NXc + 1) / 2;         // 294912
static const size_t QBF_OFF_F = UP_OFF_F + UP_F_CNT;                 // bf16 int q [B,H,S,64]
static const size_t HALF_CNT  = ((size_t)M_ * NXc + 1) / 2;          // 3145728
static const size_t KBF_OFF_F = QBF_OFF_F + HALF_CNT;                // bf16 int k [B,H,S,64]
static const size_t VBT_OFF_F = KBF_OFF_F + HALF_CNT;                // bf16 int v^T [B,H,64,S]
static const size_t ABF_OFF_F = VBT_OFF_F + HALF_CNT;                // bf16 attn out [B,S,NX]
                                                                     // (ALSO: xhi before attn)
static const size_t SC_OFF    = ABF_OFF_F + HALF_CNT;
static const size_t WS_FLOATS_NEEDED = SC_OFF + 2;                   // ~13.8M floats (55MB)

// ---------------- max |tanh(w)| reduction, both weights in one launch --------
__global__ void k_maxtanh2(const float* __restrict__ wa, const float* __restrict__ wp,
                           unsigned int* __restrict__ out) {
  const int which = blockIdx.y;
  const float* w = which ? wp : wa;
  const int n = which ? (NXc * NXc) : (NXc * NQKV);
  float mx = 0.f;
  for (int i = blockIdx.x * blockDim.x + threadIdx.x; i < n;
       i += gridDim.x * blockDim.x)
    mx = fmaxf(mx, fabsf(tanhf(w[i])));
#pragma unroll
  for (int off = 32; off > 0; off >>= 1)
    mx = fmaxf(mx, __shfl_xor(mx, off));
  if ((threadIdx.x & 63) == 0)
    atomicMax(out + which, __float_as_uint(mx));   // floats >= 0: uint order == float order
}

// ---------------- DoReFa weight quant -> transposed exact-bf16 integer weights ----
__global__ __launch_bounds__(256) void k_quantw_t(
    const float* __restrict__ w, unsigned short* __restrict__ ut,
    int K, int N, const unsigned int* __restrict__ gmax_bits) {
  __shared__ unsigned short Ut[64][72];
  const float inv2m = 0.5f / __uint_as_float(*gmax_bits);
  const int k0 = blockIdx.y * 64, n0 = blockIdx.x * 64;
  const int t = threadIdx.x;
  const int r = t >> 4, c4 = (t & 15) * 4;
#pragma unroll
  for (int rr = 0; rr < 4; ++rr) {
    int row = rr * 16 + r;
    float4 f = *(const float4*)(w + (size_t)(k0 + row) * N + n0 + c4);
    float fv[4] = {f.x, f.y, f.z, f.w};
#pragma unroll
    for (int j = 0; j < 4; ++j) {
      float tq = tanhf(fv[j]) * inv2m + 0.5f;
      float u = 2.0f * rintf(tq * 255.0f) - 255.0f;
      Ut[c4 + j][row] = f2bf(u);
    }
  }
  __syncthreads();
#pragma unroll
  for (int rep = 0; rep < 2; ++rep) {
    int c = t + rep * 256;
    int n = c >> 3, slot = c & 7;
    short8 v = *(const short8*)&Ut[n][slot * 8];
    *(short8*)(ut + (size_t)(n0 + n) * K + k0 + slot * 8) = v;
  }
}

// ---------------- x -> hi/lo bf16 split (once) ----------------
__global__ __launch_bounds__(256) void k_split(
    const float* __restrict__ x, unsigned short* __restrict__ xhi,
    unsigned short* __restrict__ xlo, int n8) {
  int i = blockIdx.x * 256 + threadIdx.x;
  if (i >= n8) return;
  const float* src = x + (size_t)i * 8;
  float4 f0 = *(const float4*)src;
  float4 f1 = *(const float4*)(src + 4);
  float fv[8] = {f0.x, f0.y, f0.z, f0.w, f1.x, f1.y, f1.z, f1.w};
  union { short8 v; unsigned short u[8]; } hi, lo;
#pragma unroll
  for (int j = 0; j < 8; ++j) {
    unsigned short hh = f2bf(fv[j]);
    hi.u[j] = hh;
    lo.u[j] = f2bf(fv[j] - bf2f(hh));
  }
  *(short8*)(xhi + (size_t)i * 8) = hi.v;
  *(short8*)(xlo + (size_t)i * 8) = lo.v;
}

// ---------------- qkv GEMM: 128x256 tile, 512 thr, BK=32, double-buffered -----
// 2-phase pipeline (T3-min): one __syncthreads per K-step; its implicit vmcnt(0)
// drains the PREFETCHED stage issued right after the previous barrier, so load
// latency hides under the current tile's ds_read+MFMA.
// Read swizzle chunk^((row>>1)&3): per quarter-wave each 16B slot hit by exactly
// 2 lanes (the bank-uniform minimum at 64B rows).
// part = bn/3 (block-uniform): 0=q (hi only), 1=k, 2=v.
__global__ __launch_bounds__(512, 4) void k_gemm_qkv(
    const unsigned short* __restrict__ xhi, const unsigned short* __restrict__ xlo,
    const unsigned short* __restrict__ ua, const float* __restrict__ bias,
    unsigned short* __restrict__ qbf, unsigned short* __restrict__ kbf,
    unsigned short* __restrict__ vbt, float* __restrict__ kq, float* __restrict__ vq) {
  __shared__ __align__(16) unsigned short Ah[2][128 * 32];   // 16 KB
  __shared__ __align__(16) unsigned short Al[2][128 * 32];   // 16 KB
  __shared__ __align__(16) unsigned short Bs[2][256 * 32];   // 32 KB  (total 64 KB)

  const int bid = blockIdx.x;                  // 576 blocks, 576%8==0
  const int swz = (bid & 7) * 72 + (bid >> 3); // XCD-pinned chunks walk bn fastest
  const int bm = swz / 9, bn = swz % 9;
  const int part = bn / 3;                     // block-uniform
  const bool do_lo = (part != 0);              // q needs no exactness

  const int t = threadIdx.x;
  const int w = t >> 6, lane = t & 63;
  const int wm = w >> 2, wn = w & 3;           // 2x4 waves of 64x64
  const int g = lane >> 4, ln = lane & 15;

  const unsigned short* Ahb = xhi + (size_t)bm * 128 * NXc;
  const unsigned short* Alb = xlo + (size_t)bm * 128 * NXc;
  const unsigned short* Bb  = ua + (size_t)bn * 256 * NXc;

  // staging geometry (per-thread constants)
  const int ar  = t >> 2,         aco = ((t & 3) ^ ((ar >> 1) & 3)) << 3;
  const int br1 = 128 + (t >> 2); // B rep-1 row (rep0 row == ar)
  const int rsw = (g ^ ((ln >> 1) & 3)) << 3;  // read-side chunk swizzle

  f32x4 acc[4][4];
#pragma unroll
  for (int i = 0; i < 4; ++i)
#pragma unroll
    for (int j = 0; j < 4; ++j) acc[i][j] = (f32x4)(0.f);

  // prologue: stage tile 0 -> buf 0
  {
    const size_t ka = (size_t)ar * NXc + aco;
    gl_lds16(Ahb + ka, &Ah[0][t * 8]);
    if (do_lo) gl_lds16(Alb + ka, &Al[0][t * 8]);
    gl_lds16(Bb + ka, &Bs[0][t * 8]);
    gl_lds16(Bb + (size_t)br1 * NXc + aco, &Bs[0][(512 + t) * 8]);
  }

  for (int tk = 0; tk < 24; ++tk) {
    __syncthreads();               // drains stage(tk); prior tile's reads done
    const int cur = tk & 1;
    if (tk + 1 < 24) {             // prefetch tile tk+1 into other buffer
      const int nb = cur ^ 1;
      const int k0 = (tk + 1) * 32;
      const size_t ka = (size_t)ar * NXc + k0 + aco;
      gl_lds16(Ahb + ka, &Ah[nb][t * 8]);
      if (do_lo) gl_lds16(Alb + ka, &Al[nb][t * 8]);
      gl_lds16(Bb + ka, &Bs[nb][t * 8]);
      gl_lds16(Bb + (size_t)br1 * NXc + k0 + aco, &Bs[nb][(512 + t) * 8]);
    }

    short8 bfrag[4];
#pragma unroll
    for (int nf = 0; nf < 4; ++nf) {
      int n = wn * 64 + nf * 16 + ln;
      bfrag[nf] = *(const short8*)&Bs[cur][n * 32 + rsw];
    }
#pragma unroll
    for (int mf = 0; mf < 4; ++mf) {
      int r = wm * 64 + mf * 16 + ln;
      short8 ah = *(const short8*)&Ah[cur][r * 32 + rsw];
#pragma unroll
      for (int nf = 0; nf < 4; ++nf)
        acc[mf][nf] = __builtin_amdgcn_mfma_f32_16x16x32_bf16(ah, bfrag[nf], acc[mf][nf], 0, 0, 0);
    }
    if (do_lo) {
#pragma unroll
      for (int mf = 0; mf < 4; ++mf) {
        int r = wm * 64 + mf * 16 + ln;
        short8 al = *(const short8*)&Al[cur][r * 32 + rsw];
#pragma unroll
        for (int nf = 0; nf < 4; ++nf)
          acc[mf][nf] = __builtin_amdgcn_mfma_f32_16x16x32_bf16(al, bfrag[nf], acc[mf][nf], 0, 0, 0);
      }
    }
  }

  const float inv255 = 1.0f / 255.0f;
#pragma unroll
  for (int mf = 0; mf < 4; ++mf) {
    int row0 = bm * 128 + wm * 64 + mf * 16 + g * 4;
#pragma unroll
    for (int nf = 0; nf < 4; ++nf) {
      int col = bn * 256 + wn * 64 + nf * 16 + ln;
      float bv = bias[col];
      int ff = col - part * NXc;
      int h = ff >> 6, d = ff & 63;
#pragma unroll
      for (int r = 0; r < 4; ++r) {
        float x = acc[mf][nf][r] * inv255 + bv;
        int row = row0 + r;
        int b = row >> 10, s = row & 1023;
        float y255 = rintf(fminf(fmaxf(x, 0.f), 1.f) * 255.0f);
        unsigned short ybf = f2bf(y255);
        size_t dst = (((size_t)b * H_ + h) * S_ + s) * HDc + d;
        if (part == 0) {
          qbf[dst] = ybf;
        } else if (part == 1) {
          kq[dst] = y255 * inv255;
          kbf[dst] = ybf;
        } else {
          vq[dst] = y255 * inv255;
          vbt[(((size_t)b * H_ + h) * HDc + d) * S_ + s] = ybf;   // transposed
        }
      }
    }
  }
}

// ---------------- proj GEMM: 128x128 tile, 256 thr, BK=32, double-buffered ----
__global__ __launch_bounds__(256, 4) void k_gemm_proj(
    const unsigned short* __restrict__ abf, const unsigned short* __restrict__ up,
    const float* __restrict__ bias, float* __restrict__ Cout) {
  __shared__ __align__(16) unsigned short Ah[2][128 * 32];   // 16 KB
  __shared__ __align__(16) unsigned short Bs[2][128 * 32];   // 16 KB

  const int bid = blockIdx.x;                  // 384 blocks, 384%8==0
  const int swz = (bid & 7) * 48 + (bid >> 3);
  const int bm = swz / 6, bn = swz % 6;

  const int t = threadIdx.x;
  const int w = t >> 6, lane = t & 63;
  const int wm = w >> 1, wn = w & 1;           // 2x2 waves of 64x64
  const int g = lane >> 4, ln = lane & 15;

  const unsigned short* Ab = abf + (size_t)bm * 128 * NXc;
  const unsigned short* Bb = up + (size_t)bn * 128 * NXc;

  const int ar0 = t >> 2, aco0 = ((t & 3) ^ ((ar0 >> 1) & 3)) << 3;
  const int ar1 = 64 + (t >> 2);               // rep-1 rows (aco same: +64 rows keeps (t&3) ^ ...)
  const int aco1 = ((t & 3) ^ ((ar1 >> 1) & 3)) << 3;
  const int rsw = (g ^ ((ln >> 1) & 3)) << 3;

  f32x4 acc[4][4];
#pragma unroll
  for (int i = 0; i < 4; ++i)
#pragma unroll
    for (int j = 0; j < 4; ++j) acc[i][j] = (f32x4)(0.f);

  {
    gl_lds16(Ab + (size_t)ar0 * NXc + aco0, &Ah[0][t * 8]);
    gl_lds16(Ab + (size_t)ar1 * NXc + aco1, &Ah[0][(256 + t) * 8]);
    gl_lds16(Bb + (size_t)ar0 * NXc + aco0, &Bs[0][t * 8]);
    gl_lds16(Bb + (size_t)ar1 * NXc + aco1, &Bs[0][(256 + t) * 8]);
  }

  for (int tk = 0; tk < 24; ++tk) {
    __syncthreads();
    const int cur = tk & 1;
    if (tk + 1 < 24) {
      const int nb = cur ^ 1;
      const int k0 = (tk + 1) * 32;
      gl_lds16(Ab + (size_t)ar0 * NXc + k0 + aco0, &Ah[nb][t * 8]);
      gl_lds16(Ab + (size_t)ar1 * NXc + k0 + aco1, &Ah[nb][(256 + t) * 8]);
      gl_lds16(Bb + (size_t)ar0 * NXc + k0 + aco0, &Bs[nb][t * 8]);
      gl_lds16(Bb + (size_t)ar1 * NXc + k0 + aco1, &Bs[nb][(256 + t) * 8]);
    }

    short8 bfrag[4];
#pragma unroll
    for (int nf = 0; nf < 4; ++nf) {
      int n = wn * 64 + nf * 16 + ln;
      bfrag[nf] = *(const short8*)&Bs[cur][n * 32 + rsw];
    }
#pragma unroll
    for (int mf = 0; mf < 4; ++mf) {
      int r = wm * 64 + mf * 16 + ln;
      short8 ah = *(const short8*)&Ah[cur][r * 32 + rsw];
#pragma unroll
      for (int nf = 0; nf < 4; ++nf)
        acc[mf][nf] = __builtin_amdgcn_mfma_f32_16x16x32_bf16(ah, bfrag[nf], acc[mf][nf], 0, 0, 0);
    }
  }

  const float inv255 = 1.0f / 255.0f;
#pragma unroll
  for (int mf = 0; mf < 4; ++mf) {
    int row0 = bm * 128 + wm * 64 + mf * 16 + g * 4;
#pragma unroll
    for (int nf = 0; nf < 4; ++nf) {
      int col = bn * 128 + wn * 64 + nf * 16 + ln;
      float bv = bias[col];
#pragma unroll
      for (int r = 0; r < 4; ++r)
        Cout[(size_t)(row0 + r) * NXc + col] = acc[mf][nf][r] * inv255 + bv;
    }
  }
}

// ---------------- MFMA causal flash attention (paired q-blocks) ----------------
// grid (8, H, B), 256 thr (4 waves x 16 q-rows). WG p handles q-blocks {p, 15-p}
// -> exactly 17 kv-tiles per WG (perfect balance). All operands bf16 integers.
// QK^T exact (sums < 2^23). P bf16-only. V read from pre-transposed vbt.
__global__ __launch_bounds__(256) void k_attn_pair(
    const unsigned short* __restrict__ qbf, const unsigned short* __restrict__ kbf,
    const unsigned short* __restrict__ vbt, unsigned short* __restrict__ abf) {
  __shared__ __align__(16) unsigned short Ks[64 * 64];      // [kv][d] ^ ((kv&7)<<3)
  __shared__ __align__(16) unsigned short Vt[64 * 64];      // [d][kv] ^ ((d&7)<<3)
  __shared__ __align__(16) unsigned short Pp[4 * 16 * 64];  // per-wave [q][kv] ^ ((q&7)<<3)

  const int p = blockIdx.x, h = blockIdx.y, b = blockIdx.z;
  const size_t hoff = ((size_t)(b * H_ + h)) * S_ * HDc;  // same elem count for [s][d] and [d][s]
  const unsigned short* qh = qbf + hoff;
  const unsigned short* kh = kbf + hoff;
  const unsigned short* vh = vbt + hoff;

  const int t = threadIdx.x;
  const int w = t >> 6, lane = t & 63;
  const int g = lane >> 4, ln = lane & 15;

  const float SCALE = 1.0f / (255.0f * 255.0f * 8.0f);

  for (int ph = 0; ph < 2; ++ph) {
    const int iq = ph ? 15 - p : p;

    // Q fragments: rows iq*64 + w*16 + ln (integer-scaled bf16)
    const unsigned short* qr = qh + (size_t)(iq * 64 + w * 16 + ln) * HDc;
    short8 qfrag[2];
    qfrag[0] = *(const short8*)(qr + g * 8);
    qfrag[1] = *(const short8*)(qr + 32 + g * 8);

    float m[4], l[4];
    f32x4 accO[4];
#pragma unroll
    for (int r = 0; r < 4; ++r) { m[r] = -1e30f; l[r] = 0.f; }
#pragma unroll
    for (int nf = 0; nf < 4; ++nf) accO[nf] = (f32x4)(0.f);

    for (int jb = 0; jb <= iq; ++jb) {
      __syncthreads();   // previous tile's LDS reads complete
#pragma unroll
      for (int rep = 0; rep < 2; ++rep) {
        int e = t + rep * 256;
        int row = e >> 3, slot = e & 7;
        short8 kk = *(const short8*)(kh + (size_t)(jb * 64 + row) * HDc + slot * 8);
        *(short8*)&Ks[row * 64 + ((slot * 8) ^ ((row & 7) << 3))] = kk;
        short8 vv = *(const short8*)(vh + (size_t)row * S_ + jb * 64 + slot * 8);
        *(short8*)&Vt[row * 64 + ((slot * 8) ^ ((row & 7) << 3))] = vv;
      }
      __syncthreads();

      // QK^T (exact integer)
      f32x4 accS[4];
#pragma unroll
      for (int nf = 0; nf < 4; ++nf) accS[nf] = (f32x4)(0.f);
#pragma unroll
      for (int ks = 0; ks < 2; ++ks)
#pragma unroll
        for (int nf = 0; nf < 4; ++nf) {
          int kvr = nf * 16 + ln;
          short8 bk = *(const short8*)&Ks[kvr * 64 + ((ks * 32 + g * 8) ^ ((kvr & 7) << 3))];
          accS[nf] = __builtin_amdgcn_mfma_f32_16x16x32_bf16(qfrag[ks], bk, accS[nf], 0, 0, 0);
        }

      // scale + causal mask (rows g*4+r, cols nf*16+ln)
      float sv[4][4];
      if (jb == iq) {
        const int grow = iq * 64 + w * 16 + g * 4;
        const int gcol = jb * 64 + ln;
#pragma unroll
        for (int nf = 0; nf < 4; ++nf)
#pragma unroll
          for (int r = 0; r < 4; ++r)
            sv[nf][r] = (gcol + nf * 16 > grow + r) ? -1e30f : accS[nf][r] * SCALE;
      } else {
#pragma unroll
        for (int nf = 0; nf < 4; ++nf)
#pragma unroll
          for (int r = 0; r < 4; ++r) sv[nf][r] = accS[nf][r] * SCALE;
      }

      // online softmax (rows g*4+r shared by the 16 ln-lanes)
      float mt[4];
#pragma unroll
      for (int r = 0; r < 4; ++r)
        mt[r] = fmaxf(fmaxf(sv[0][r], sv[1][r]), fmaxf(sv[2][r], sv[3][r]));
#pragma unroll
      for (int off = 1; off < 16; off <<= 1)
#pragma unroll
        for (int r = 0; r < 4; ++r) mt[r] = fmaxf(mt[r], __shfl_xor(mt[r], off));

      float pr[4][4], rs[4];
#pragma unroll
      for (int r = 0; r < 4; ++r) {
        float mn = fmaxf(m[r], mt[r]);
        float corr = __expf(m[r] - mn);
        m[r] = mn;
        l[r] *= corr;
#pragma unroll
        for (int nf = 0; nf < 4; ++nf) accO[nf][r] *= corr;
        float sum = 0.f;
#pragma unroll
        for (int nf = 0; nf < 4; ++nf) {
          float pv = __expf(sv[nf][r] - mn);
          pr[nf][r] = pv;
          sum += pv;
        }
        rs[r] = sum;
      }
#pragma unroll
      for (int off = 1; off < 16; off <<= 1)
#pragma unroll
        for (int r = 0; r < 4; ++r) rs[r] += __shfl_xor(rs[r], off);
#pragma unroll
      for (int r = 0; r < 4; ++r) l[r] += rs[r];

      // P -> LDS (bf16, within-wave round trip, no barrier)
#pragma unroll
      for (int nf = 0; nf < 4; ++nf)
#pragma unroll
        for (int r = 0; r < 4; ++r) {
          int prow = g * 4 + r;
          Pp[w * 1024 + prow * 64 + ((nf * 16 + ln) ^ ((prow & 7) << 3))] = f2bf(pr[nf][r]);
        }

      // PV: accO[nf] += P(16x32) * V(32x16)
#pragma unroll
      for (int ks = 0; ks < 2; ++ks) {
        short8 pa = *(const short8*)&Pp[w * 1024 + ln * 64 + ((ks * 32 + g * 8) ^ ((ln & 7) << 3))];
#pragma unroll
        for (int nf = 0; nf < 4; ++nf) {
          int d = nf * 16 + ln;
          short8 bv = *(const short8*)&Vt[d * 64 + ((ks * 32 + g * 8) ^ ((d & 7) << 3))];
          accO[nf] = __builtin_amdgcn_mfma_f32_16x16x32_bf16(pa, bv, accO[nf], 0, 0, 0);
        }
      }
    }

    // write attn-out bf16 [B,S,NX]; accO rows q=g*4+r, cols d=nf*16+ln; V scaled x255
#pragma unroll
    for (int r = 0; r < 4; ++r) {
      float inv = 1.0f / (255.0f * l[r]);
      size_t row = (size_t)b * S_ + iq * 64 + w * 16 + g * 4 + r;
#pragma unroll
      for (int nf = 0; nf < 4; ++nf)
        abf[row * NXc + h * HDc + nf * 16 + ln] = f2bf(accO[nf][r] * inv);
    }
  }
}

// ---------------- host launcher ----------------
extern "C" void kernel_launch(void* const* d_in, const int* in_sizes, int n_in,
                              void* d_out, int out_size, void* d_ws, size_t ws_size,
                              hipStream_t stream) {
  const float* x      = (const float*)d_in[0];
  const float* W_attn = (const float*)d_in[1];
  const float* b_attn = (const float*)d_in[2];
  const float* W_proj = (const float*)d_in[3];
  const float* b_proj = (const float*)d_in[4];

  float* out = (float*)d_out;
  float* ws  = (float*)d_ws;
  if (ws_size < WS_FLOATS_NEEDED * sizeof(float)) return;

  float* a_out = out;                               // [B,S,NX]
  float* k_out = out + (size_t)M_ * NXc;            // present[0] = k  [B,H,S,hd]
  float* v_out = k_out + (size_t)M_ * NXc;          // present[1] = v

  unsigned short* ua  = (unsigned short*)(ws + UA_OFF_F);
  unsigned short* up  = (unsigned short*)(ws + UP_OFF_F);
  unsigned short* qbf = (unsigned short*)(ws + QBF_OFF_F);
  unsigned short* kbf = (unsigned short*)(ws + KBF_OFF_F);
  unsigned short* vbt = (unsigned short*)(ws + VBT_OFF_F);
  unsigned short* abf = (unsigned short*)(ws + ABF_OFF_F);
  unsigned int* sc = (unsigned int*)(ws + SC_OFF);

  // region reuse (stream-serial, all fully rewritten before their real use):
  //   xhi lives in abf's slot (attn writes abf only AFTER qkv GEMM consumed xhi)
  //   xlo lives in a_out (proj writes a_out only AFTER qkv GEMM consumed xlo)
  unsigned short* xhi = abf;
  unsigned short* xlo = (unsigned short*)a_out;

  hipMemsetAsync(sc, 0, 2 * sizeof(unsigned int), stream);

  k_maxtanh2<<<dim3(128, 2), 256, 0, stream>>>(W_attn, W_proj, sc);

  k_quantw_t<<<dim3(NQKV / 64, NXc / 64), 256, 0, stream>>>(W_attn, ua, NXc, NQKV, sc);
  k_quantw_t<<<dim3(NXc / 64, NXc / 64), 256, 0, stream>>>(W_proj, up, NXc, NXc, sc + 1);

  // x -> hi/lo bf16 (once)
  k_split<<<(M_ * NXc / 8 + 255) / 256, 256, 0, stream>>>(x, xhi, xlo, M_ * NXc / 8);

  // qkv = x @ wq_attn + b_attn; emits bf16 q,k,v^T + fp32 present
  k_gemm_qkv<<<(NQKV / 256) * (M_ / 128), 512, 0, stream>>>(
      xhi, xlo, ua, b_attn, qbf, kbf, vbt, k_out, v_out);

  // causal attention (paired q-blocks, all-bf16) — overwrites xhi region with abf
  k_attn_pair<<<dim3(8, H_, B_), 256, 0, stream>>>(qbf, kbf, vbt, abf);

  // a = attn_out @ wq_proj + b_proj (bf16 A) — overwrites xlo region
  k_gemm_proj<<<(NXc / 128) * (M_ / 128), 256, 0, stream>>>(abf, up, b_proj, a_out);
}

// Round 8
// 208.435 us; speedup vs baseline: 1.0183x; 1.0183x over previous
//
#include <hip/hip_runtime.h>
#include <math.h>

#define B_   8
#define S_   1024
#define NXc  768
#define H_   12
#define HDc  64
#define M_   (B_*S_)        // 8192
#define NQKV (3*NXc)        // 2304

typedef __attribute__((ext_vector_type(8))) short short8;
typedef __attribute__((ext_vector_type(8))) _Float16 half8;
typedef __attribute__((ext_vector_type(4))) float f32x4;

__device__ inline unsigned short f2h(float f) {
  union { _Float16 h; unsigned short u; } c;
  c.h = (_Float16)f;                 // RNE
  return c.u;
}

__device__ inline void gl_lds16(const unsigned short* g, unsigned short* l) {
  __builtin_amdgcn_global_load_lds(
      (const __attribute__((address_space(1))) void*)g,
      (__attribute__((address_space(3))) void*)l, 16, 0, 0);
}

// ---- workspace layout (floats) ----
// All "exact integer" tensors stored as fp16 (ints <= 255 are exact in fp16).
static const size_t UA_OFF_F  = 0;                                   // fp16 Ut attn [NQKV][NXc]
static const size_t UA_F_CNT  = ((size_t)NQKV * NXc + 1) / 2;        // 884736
static const size_t UP_OFF_F  = UA_OFF_F + UA_F_CNT;                 // fp16 Ut proj [NXc][NXc]
static const size_t UP_F_CNT  = ((size_t)NXc * NXc + 1) / 2;         // 294912
static const size_t QH_OFF_F  = UP_OFF_F + UP_F_CNT;                 // fp16 int q [B,H,S,64]
static const size_t HALF_CNT  = ((size_t)M_ * NXc + 1) / 2;          // 3145728
static const size_t KH_OFF_F  = QH_OFF_F + HALF_CNT;                 // fp16 int k [B,H,S,64]
static const size_t VHT_OFF_F = KH_OFF_F + HALF_CNT;                 // fp16 int v^T [B,H,64,S]
static const size_t AHF_OFF_F = VHT_OFF_F + HALF_CNT;                // fp16 attn out [B,S,NX]
                                                                     // (ALSO: xh before attn)
static const size_t SC_OFF    = AHF_OFF_F + HALF_CNT;
static const size_t WS_FLOATS_NEEDED = SC_OFF + 2;

// ---------------- max |tanh(w)| reduction, both weights in one launch --------
__global__ void k_maxtanh2(const float* __restrict__ wa, const float* __restrict__ wp,
                           unsigned int* __restrict__ out) {
  const int which = blockIdx.y;
  const float* w = which ? wp : wa;
  const int n = which ? (NXc * NXc) : (NXc * NQKV);
  float mx = 0.f;
  for (int i = blockIdx.x * blockDim.x + threadIdx.x; i < n;
       i += gridDim.x * blockDim.x)
    mx = fmaxf(mx, fabsf(tanhf(w[i])));
#pragma unroll
  for (int off = 32; off > 0; off >>= 1)
    mx = fmaxf(mx, __shfl_xor(mx, off));
  if ((threadIdx.x & 63) == 0)
    atomicMax(out + which, __float_as_uint(mx));   // floats >= 0: uint order == float order
}

// ---------------- DoReFa weight quant -> transposed exact-fp16 integer weights ----
// Ut[n][k] = 2*round(t*255) - 255 (odd, |u|<=255 -> exact fp16)
__global__ __launch_bounds__(256) void k_quantw_t(
    const float* __restrict__ w, unsigned short* __restrict__ ut,
    int K, int N, const unsigned int* __restrict__ gmax_bits) {
  __shared__ unsigned short Ut[64][72];
  const float inv2m = 0.5f / __uint_as_float(*gmax_bits);
  const int k0 = blockIdx.y * 64, n0 = blockIdx.x * 64;
  const int t = threadIdx.x;
  const int r = t >> 4, c4 = (t & 15) * 4;
#pragma unroll
  for (int rr = 0; rr < 4; ++rr) {
    int row = rr * 16 + r;
    float4 f = *(const float4*)(w + (size_t)(k0 + row) * N + n0 + c4);
    float fv[4] = {f.x, f.y, f.z, f.w};
#pragma unroll
    for (int j = 0; j < 4; ++j) {
      float tq = tanhf(fv[j]) * inv2m + 0.5f;
      float u = 2.0f * rintf(tq * 255.0f) - 255.0f;
      Ut[c4 + j][row] = f2h(u);
    }
  }
  __syncthreads();
#pragma unroll
  for (int rep = 0; rep < 2; ++rep) {
    int c = t + rep * 256;
    int n = c >> 3, slot = c & 7;
    short8 v = *(const short8*)&Ut[n][slot * 8];
    *(short8*)(ut + (size_t)(n0 + n) * K + k0 + slot * 8) = v;
  }
}

// ---------------- x -> fp16 (once) ----------------
__global__ __launch_bounds__(256) void k_xhalf(
    const float* __restrict__ x, unsigned short* __restrict__ xh, int n8) {
  int i = blockIdx.x * 256 + threadIdx.x;
  if (i >= n8) return;
  const float* src = x + (size_t)i * 8;
  float4 f0 = *(const float4*)src;
  float4 f1 = *(const float4*)(src + 4);
  float fv[8] = {f0.x, f0.y, f0.z, f0.w, f1.x, f1.y, f1.z, f1.w};
  union { short8 v; unsigned short u[8]; } o;
#pragma unroll
  for (int j = 0; j < 8; ++j) o.u[j] = f2h(fv[j]);
  *(short8*)(xh + (size_t)i * 8) = o.v;
}

// ---------------- qkv GEMM: fp16 single-pass MFMA -------------------------
// 128x256 tile, 256 thr (4 waves, each 64 rows x 128 cols), BK=32, dbuf (48 KB).
// gl_lds staging, both-sides chunk swizzle (conflict-free, measured 0 in r7).
// XCD swizzle: 576 blocks, 72/XCD, consecutive swz share bm -> A panels XCD-local.
// part = bn/3 block-uniform: 0=q, 1=k, 2=v.
__global__ __launch_bounds__(256, 2) void k_gemm_qkv(
    const unsigned short* __restrict__ xh, const unsigned short* __restrict__ ua,
    const float* __restrict__ bias,
    unsigned short* __restrict__ qh, unsigned short* __restrict__ kh,
    unsigned short* __restrict__ vht,
    float* __restrict__ kq, float* __restrict__ vq) {
  __shared__ __align__(16) unsigned short Ah[2][128 * 32];   // 16 KB
  __shared__ __align__(16) unsigned short Bs[2][256 * 32];   // 32 KB

  const int bid = blockIdx.x;                  // 576, %8==0
  const int swz = (bid & 7) * 72 + (bid >> 3);
  const int bm = swz / 9, bn = swz % 9;
  const int part = bn / 3;

  const int t = threadIdx.x;
  const int w = t >> 6, lane = t & 63;
  const int wm = w >> 1, wn = w & 1;           // wave tile 64 x 128
  const int g = lane >> 4, ln = lane & 15;

  const unsigned short* Ab = xh + (size_t)bm * 128 * NXc;
  const unsigned short* Bb = ua + (size_t)bn * 256 * NXc;

  const int arow = t >> 2;                         // 0..63
  const int aco  = (((t & 3) ^ ((t >> 3) & 3)) << 3);
  const int rsw  = ((g ^ ((ln >> 1) & 3)) << 3);   // read-side chunk swizzle

  f32x4 acc[4][8];
#pragma unroll
  for (int i = 0; i < 4; ++i)
#pragma unroll
    for (int j = 0; j < 8; ++j) acc[i][j] = (f32x4)(0.f);

  // prologue: stage tile 0 -> buf 0
  {
    gl_lds16(Ab + (size_t)arow * NXc + aco, &Ah[0][t * 8]);
    gl_lds16(Ab + (size_t)(arow + 64) * NXc + aco, &Ah[0][(256 + t) * 8]);
#pragma unroll
    for (int r = 0; r < 4; ++r)
      gl_lds16(Bb + (size_t)(arow + r * 64) * NXc + aco, &Bs[0][(r * 256 + t) * 8]);
  }

  for (int tk = 0; tk < 24; ++tk) {
    __syncthreads();               // drains stage(tk); prior tile's reads done
    const int cur = tk & 1;
    if (tk + 1 < 24) {
      const int nb = cur ^ 1;
      const int k0 = (tk + 1) * 32;
      gl_lds16(Ab + (size_t)arow * NXc + k0 + aco, &Ah[nb][t * 8]);
      gl_lds16(Ab + (size_t)(arow + 64) * NXc + k0 + aco, &Ah[nb][(256 + t) * 8]);
#pragma unroll
      for (int r = 0; r < 4; ++r)
        gl_lds16(Bb + (size_t)(arow + r * 64) * NXc + k0 + aco, &Bs[nb][(r * 256 + t) * 8]);
    }

    half8 bfrag[8];
#pragma unroll
    for (int nf = 0; nf < 8; ++nf)
      bfrag[nf] = *(const half8*)&Bs[cur][(wn * 128 + nf * 16 + ln) * 32 + rsw];
#pragma unroll
    for (int mf = 0; mf < 4; ++mf) {
      half8 ah = *(const half8*)&Ah[cur][(wm * 64 + mf * 16 + ln) * 32 + rsw];
#pragma unroll
      for (int nf = 0; nf < 8; ++nf)
        acc[mf][nf] = __builtin_amdgcn_mfma_f32_16x16x32_f16(ah, bfrag[nf], acc[mf][nf], 0, 0, 0);
    }
  }

  const float inv255 = 1.0f / 255.0f;
#pragma unroll
  for (int mf = 0; mf < 4; ++mf) {
    int row0 = bm * 128 + wm * 64 + mf * 16 + g * 4;
#pragma unroll
    for (int nf = 0; nf < 8; ++nf) {
      int col = bn * 256 + wn * 128 + nf * 16 + ln;
      float bv = bias[col];
      int ff = col - part * NXc;
      int h = ff >> 6, d = ff & 63;
#pragma unroll
      for (int r = 0; r < 4; ++r) {
        float x = acc[mf][nf][r] * inv255 + bv;
        int row = row0 + r;
        int b = row >> 10, s = row & 1023;
        float y255 = rintf(fminf(fmaxf(x, 0.f), 1.f) * 255.0f);
        unsigned short yh = f2h(y255);       // exact fp16 integer
        size_t dst = (((size_t)b * H_ + h) * S_ + s) * HDc + d;
        if (part == 0) {
          qh[dst] = yh;
        } else if (part == 1) {
          kq[dst] = y255 * inv255;
          kh[dst] = yh;
        } else {
          vq[dst] = y255 * inv255;
          vht[(((size_t)b * H_ + h) * HDc + d) * S_ + s] = yh;   // transposed
        }
      }
    }
  }
}

// ---------------- proj GEMM: fp16, 128x256 tile, dbuf --------------------
__global__ __launch_bounds__(256, 2) void k_gemm_proj(
    const unsigned short* __restrict__ ahf, const unsigned short* __restrict__ up,
    const float* __restrict__ bias, float* __restrict__ Cout) {
  __shared__ __align__(16) unsigned short Ah[2][128 * 32];
  __shared__ __align__(16) unsigned short Bs[2][256 * 32];

  const int bid = blockIdx.x;                  // 192, %8==0
  const int swz = (bid & 7) * 24 + (bid >> 3);
  const int bm = swz / 3, bn = swz % 3;

  const int t = threadIdx.x;
  const int w = t >> 6, lane = t & 63;
  const int wm = w >> 1, wn = w & 1;
  const int g = lane >> 4, ln = lane & 15;

  const unsigned short* Ab = ahf + (size_t)bm * 128 * NXc;
  const unsigned short* Bb = up + (size_t)bn * 256 * NXc;

  const int arow = t >> 2;
  const int aco  = (((t & 3) ^ ((t >> 3) & 3)) << 3);
  const int rsw  = ((g ^ ((ln >> 1) & 3)) << 3);

  f32x4 acc[4][8];
#pragma unroll
  for (int i = 0; i < 4; ++i)
#pragma unroll
    for (int j = 0; j < 8; ++j) acc[i][j] = (f32x4)(0.f);

  {
    gl_lds16(Ab + (size_t)arow * NXc + aco, &Ah[0][t * 8]);
    gl_lds16(Ab + (size_t)(arow + 64) * NXc + aco, &Ah[0][(256 + t) * 8]);
#pragma unroll
    for (int r = 0; r < 4; ++r)
      gl_lds16(Bb + (size_t)(arow + r * 64) * NXc + aco, &Bs[0][(r * 256 + t) * 8]);
  }

  for (int tk = 0; tk < 24; ++tk) {
    __syncthreads();
    const int cur = tk & 1;
    if (tk + 1 < 24) {
      const int nb = cur ^ 1;
      const int k0 = (tk + 1) * 32;
      gl_lds16(Ab + (size_t)arow * NXc + k0 + aco, &Ah[nb][t * 8]);
      gl_lds16(Ab + (size_t)(arow + 64) * NXc + k0 + aco, &Ah[nb][(256 + t) * 8]);
#pragma unroll
      for (int r = 0; r < 4; ++r)
        gl_lds16(Bb + (size_t)(arow + r * 64) * NXc + k0 + aco, &Bs[nb][(r * 256 + t) * 8]);
    }

    half8 bfrag[8];
#pragma unroll
    for (int nf = 0; nf < 8; ++nf)
      bfrag[nf] = *(const half8*)&Bs[cur][(wn * 128 + nf * 16 + ln) * 32 + rsw];
#pragma unroll
    for (int mf = 0; mf < 4; ++mf) {
      half8 ah = *(const half8*)&Ah[cur][(wm * 64 + mf * 16 + ln) * 32 + rsw];
#pragma unroll
      for (int nf = 0; nf < 8; ++nf)
        acc[mf][nf] = __builtin_amdgcn_mfma_f32_16x16x32_f16(ah, bfrag[nf], acc[mf][nf], 0, 0, 0);
    }
  }

  const float inv255 = 1.0f / 255.0f;
#pragma unroll
  for (int mf = 0; mf < 4; ++mf) {
    int row0 = bm * 128 + wm * 64 + mf * 16 + g * 4;
#pragma unroll
    for (int nf = 0; nf < 8; ++nf) {
      int col = bn * 256 + wn * 128 + nf * 16 + ln;
      float bv = bias[col];
#pragma unroll
      for (int r = 0; r < 4; ++r)
        Cout[(size_t)(row0 + r) * NXc + col] = acc[mf][nf][r] * inv255 + bv;
    }
  }
}

// ---------------- MFMA causal flash attention (fp16, paired q-blocks) ---------
// grid (8, H, B), 256 thr (4 waves x 16 q-rows). WG p handles q-blocks {p, 15-p}
// -> exactly 17 kv-tiles per WG. q,k,v fp16 integers: QK^T exact (sums < 2^23).
// P fp16 (2^-11). V read from pre-transposed vht.
__global__ __launch_bounds__(256) void k_attn_pair(
    const unsigned short* __restrict__ qh, const unsigned short* __restrict__ kh,
    const unsigned short* __restrict__ vht, unsigned short* __restrict__ ahf) {
  __shared__ __align__(16) unsigned short Ks[64 * 64];      // [kv][d] ^ ((kv&7)<<3)
  __shared__ __align__(16) unsigned short Vt[64 * 64];      // [d][kv] ^ ((d&7)<<3)
  __shared__ __align__(16) unsigned short Pp[4 * 16 * 64];  // per-wave [q][kv] ^ ((q&7)<<3)

  const int p = blockIdx.x, h = blockIdx.y, b = blockIdx.z;
  const size_t hoff = ((size_t)(b * H_ + h)) * S_ * HDc;
  const unsigned short* qhp = qh + hoff;
  const unsigned short* khp = kh + hoff;
  const unsigned short* vhp = vht + hoff;

  const int t = threadIdx.x;
  const int w = t >> 6, lane = t & 63;
  const int g = lane >> 4, ln = lane & 15;

  const float SCALE = 1.0f / (255.0f * 255.0f * 8.0f);

  for (int ph = 0; ph < 2; ++ph) {
    const int iq = ph ? 15 - p : p;

    const unsigned short* qr = qhp + (size_t)(iq * 64 + w * 16 + ln) * HDc;
    half8 qfrag[2];
    qfrag[0] = *(const half8*)(qr + g * 8);
    qfrag[1] = *(const half8*)(qr + 32 + g * 8);

    float m[4], l[4];
    f32x4 accO[4];
#pragma unroll
    for (int r = 0; r < 4; ++r) { m[r] = -1e30f; l[r] = 0.f; }
#pragma unroll
    for (int nf = 0; nf < 4; ++nf) accO[nf] = (f32x4)(0.f);

    for (int jb = 0; jb <= iq; ++jb) {
      __syncthreads();   // previous tile's LDS reads complete
#pragma unroll
      for (int rep = 0; rep < 2; ++rep) {
        int e = t + rep * 256;
        int row = e >> 3, slot = e & 7;
        short8 kk = *(const short8*)(khp + (size_t)(jb * 64 + row) * HDc + slot * 8);
        *(short8*)&Ks[row * 64 + ((slot * 8) ^ ((row & 7) << 3))] = kk;
        short8 vv = *(const short8*)(vhp + (size_t)row * S_ + jb * 64 + slot * 8);
        *(short8*)&Vt[row * 64 + ((slot * 8) ^ ((row & 7) << 3))] = vv;
      }
      __syncthreads();

      // QK^T (exact integer)
      f32x4 accS[4];
#pragma unroll
      for (int nf = 0; nf < 4; ++nf) accS[nf] = (f32x4)(0.f);
#pragma unroll
      for (int ks = 0; ks < 2; ++ks)
#pragma unroll
        for (int nf = 0; nf < 4; ++nf) {
          int kvr = nf * 16 + ln;
          half8 bk = *(const half8*)&Ks[kvr * 64 + ((ks * 32 + g * 8) ^ ((kvr & 7) << 3))];
          accS[nf] = __builtin_amdgcn_mfma_f32_16x16x32_f16(qfrag[ks], bk, accS[nf], 0, 0, 0);
        }

      // scale + causal mask (rows g*4+r, cols nf*16+ln)
      float sv[4][4];
      if (jb == iq) {
        const int grow = iq * 64 + w * 16 + g * 4;
        const int gcol = jb * 64 + ln;
#pragma unroll
        for (int nf = 0; nf < 4; ++nf)
#pragma unroll
          for (int r = 0; r < 4; ++r)
            sv[nf][r] = (gcol + nf * 16 > grow + r) ? -1e30f : accS[nf][r] * SCALE;
      } else {
#pragma unroll
        for (int nf = 0; nf < 4; ++nf)
#pragma unroll
          for (int r = 0; r < 4; ++r) sv[nf][r] = accS[nf][r] * SCALE;
      }

      // online softmax (rows g*4+r shared by the 16 ln-lanes)
      float mt[4];
#pragma unroll
      for (int r = 0; r < 4; ++r)
        mt[r] = fmaxf(fmaxf(sv[0][r], sv[1][r]), fmaxf(sv[2][r], sv[3][r]));
#pragma unroll
      for (int off = 1; off < 16; off <<= 1)
#pragma unroll
        for (int r = 0; r < 4; ++r) mt[r] = fmaxf(mt[r], __shfl_xor(mt[r], off));

      float pr[4][4], rs[4];
#pragma unroll
      for (int r = 0; r < 4; ++r) {
        float mn = fmaxf(m[r], mt[r]);
        float corr = __expf(m[r] - mn);
        m[r] = mn;
        l[r] *= corr;
#pragma unroll
        for (int nf = 0; nf < 4; ++nf) accO[nf][r] *= corr;
        float sum = 0.f;
#pragma unroll
        for (int nf = 0; nf < 4; ++nf) {
          float pv = __expf(sv[nf][r] - mn);
          pr[nf][r] = pv;
          sum += pv;
        }
        rs[r] = sum;
      }
#pragma unroll
      for (int off = 1; off < 16; off <<= 1)
#pragma unroll
        for (int r = 0; r < 4; ++r) rs[r] += __shfl_xor(rs[r], off);
#pragma unroll
      for (int r = 0; r < 4; ++r) l[r] += rs[r];

      // P -> LDS (fp16, within-wave round trip, no barrier)
#pragma unroll
      for (int nf = 0; nf < 4; ++nf)
#pragma unroll
        for (int r = 0; r < 4; ++r) {
          int prow = g * 4 + r;
          Pp[w * 1024 + prow * 64 + ((nf * 16 + ln) ^ ((prow & 7) << 3))] = f2h(pr[nf][r]);
        }

      // PV: accO[nf] += P(16x32) * V(32x16)
#pragma unroll
      for (int ks = 0; ks < 2; ++ks) {
        half8 pa = *(const half8*)&Pp[w * 1024 + ln * 64 + ((ks * 32 + g * 8) ^ ((ln & 7) << 3))];
#pragma unroll
        for (int nf = 0; nf < 4; ++nf) {
          int d = nf * 16 + ln;
          half8 bv = *(const half8*)&Vt[d * 64 + ((ks * 32 + g * 8) ^ ((d & 7) << 3))];
          accO[nf] = __builtin_amdgcn_mfma_f32_16x16x32_f16(pa, bv, accO[nf], 0, 0, 0);
        }
      }
    }

    // write attn-out fp16 [B,S,NX]; V was integer-scaled by 255
#pragma unroll
    for (int r = 0; r < 4; ++r) {
      float inv = 1.0f / (255.0f * l[r]);
      size_t row = (size_t)b * S_ + iq * 64 + w * 16 + g * 4 + r;
#pragma unroll
      for (int nf = 0; nf < 4; ++nf)
        ahf[row * NXc + h * HDc + nf * 16 + ln] = f2h(accO[nf][r] * inv);
    }
  }
}

// ---------------- host launcher ----------------
extern "C" void kernel_launch(void* const* d_in, const int* in_sizes, int n_in,
                              void* d_out, int out_size, void* d_ws, size_t ws_size,
                              hipStream_t stream) {
  const float* x      = (const float*)d_in[0];
  const float* W_attn = (const float*)d_in[1];
  const float* b_attn = (const float*)d_in[2];
  const float* W_proj = (const float*)d_in[3];
  const float* b_proj = (const float*)d_in[4];

  float* out = (float*)d_out;
  float* ws  = (float*)d_ws;
  if (ws_size < WS_FLOATS_NEEDED * sizeof(float)) return;

  float* a_out = out;                               // [B,S,NX]
  float* k_out = out + (size_t)M_ * NXc;            // present[0] = k  [B,H,S,hd]
  float* v_out = k_out + (size_t)M_ * NXc;          // present[1] = v

  unsigned short* ua  = (unsigned short*)(ws + UA_OFF_F);
  unsigned short* up  = (unsigned short*)(ws + UP_OFF_F);
  unsigned short* qh  = (unsigned short*)(ws + QH_OFF_F);
  unsigned short* kh  = (unsigned short*)(ws + KH_OFF_F);
  unsigned short* vht = (unsigned short*)(ws + VHT_OFF_F);
  unsigned short* ahf = (unsigned short*)(ws + AHF_OFF_F);
  unsigned int* sc = (unsigned int*)(ws + SC_OFF);

  // region reuse: xh lives in ahf's slot (attn writes ahf only AFTER qkv consumed xh)
  unsigned short* xh = ahf;

  hipMemsetAsync(sc, 0, 2 * sizeof(unsigned int), stream);

  k_maxtanh2<<<dim3(128, 2), 256, 0, stream>>>(W_attn, W_proj, sc);

  k_quantw_t<<<dim3(NQKV / 64, NXc / 64), 256, 0, stream>>>(W_attn, ua, NXc, NQKV, sc);
  k_quantw_t<<<dim3(NXc / 64, NXc / 64), 256, 0, stream>>>(W_proj, up, NXc, NXc, sc + 1);

  // x -> fp16 (once)
  k_xhalf<<<(M_ * NXc / 8 + 255) / 256, 256, 0, stream>>>(x, xh, M_ * NXc / 8);

  // qkv = x @ wq_attn + b_attn (fp16 MFMA); emits fp16 q,k,v^T + fp32 present
  k_gemm_qkv<<<(NQKV / 256) * (M_ / 128), 256, 0, stream>>>(
      xh, ua, b_attn, qh, kh, vht, k_out, v_out);

  // causal attention (paired q-blocks, fp16) — overwrites xh region with ahf
  k_attn_pair<<<dim3(8, H_, B_), 256, 0, stream>>>(qh, kh, vht, ahf);

  // a = attn_out @ wq_proj + b_proj (fp16 MFMA)
  k_gemm_proj<<<(NXc / 256) * (M_ / 128), 256, 0, stream>>>(ahf, up, b_proj, a_out);
}

// Round 9
// 190.712 us; speedup vs baseline: 1.1129x; 1.0929x over previous
//
#include <hip/hip_runtime.h>
#include <math.h>

#define B_   8
#define S_   1024
#define NXc  768
#define H_   12
#define HDc  64
#define M_   (B_*S_)        // 8192
#define NQKV (3*NXc)        // 2304

typedef __attribute__((ext_vector_type(8))) short short8;
typedef __attribute__((ext_vector_type(8))) _Float16 half8;
typedef __attribute__((ext_vector_type(4))) float f32x4;

__device__ inline unsigned short f2h(float f) {
  union { _Float16 h; unsigned short u; } c;
  c.h = (_Float16)f;                 // RNE
  return c.u;
}

__device__ inline void gl_lds16(const unsigned short* g, unsigned short* l) {
  __builtin_amdgcn_global_load_lds(
      (const __attribute__((address_space(1))) void*)g,
      (__attribute__((address_space(3))) void*)l, 16, 0, 0);
}

// ---- workspace layout (floats) ----
// All "exact integer" tensors stored as fp16 (ints <= 255 are exact in fp16).
static const size_t UA_OFF_F  = 0;                                   // fp16 Ut attn [NQKV][NXc]
static const size_t UA_F_CNT  = ((size_t)NQKV * NXc + 1) / 2;        // 884736
static const size_t UP_OFF_F  = UA_OFF_F + UA_F_CNT;                 // fp16 Ut proj [NXc][NXc]
static const size_t UP_F_CNT  = ((size_t)NXc * NXc + 1) / 2;         // 294912
static const size_t QH_OFF_F  = UP_OFF_F + UP_F_CNT;                 // fp16 int q [B,H,S,64]
static const size_t HALF_CNT  = ((size_t)M_ * NXc + 1) / 2;          // 3145728
static const size_t KH_OFF_F  = QH_OFF_F + HALF_CNT;                 // fp16 int k [B,H,S,64]
static const size_t VHT_OFF_F = KH_OFF_F + HALF_CNT;                 // fp16 int v^T [B,H,64,S]
static const size_t AHF_OFF_F = VHT_OFF_F + HALF_CNT;                // fp16 attn out [B,S,NX]
                                                                     // (ALSO: xh before attn)
static const size_t SC_OFF    = AHF_OFF_F + HALF_CNT;
static const size_t WS_FLOATS_NEEDED = SC_OFF + 2;

// ---------------- max |tanh(w)| reduction, both weights in one launch --------
__global__ void k_maxtanh2(const float* __restrict__ wa, const float* __restrict__ wp,
                           unsigned int* __restrict__ out) {
  const int which = blockIdx.y;
  const float* w = which ? wp : wa;
  const int n = which ? (NXc * NXc) : (NXc * NQKV);
  float mx = 0.f;
  for (int i = blockIdx.x * blockDim.x + threadIdx.x; i < n;
       i += gridDim.x * blockDim.x)
    mx = fmaxf(mx, fabsf(tanhf(w[i])));
#pragma unroll
  for (int off = 32; off > 0; off >>= 1)
    mx = fmaxf(mx, __shfl_xor(mx, off));
  if ((threadIdx.x & 63) == 0)
    atomicMax(out + which, __float_as_uint(mx));   // floats >= 0: uint order == float order
}

// ---------------- DoReFa weight quant -> transposed exact-fp16 integer weights ----
// Ut[n][k] = 2*round(t*255) - 255 (odd, |u|<=255 -> exact fp16)
__global__ __launch_bounds__(256) void k_quantw_t(
    const float* __restrict__ w, unsigned short* __restrict__ ut,
    int K, int N, const unsigned int* __restrict__ gmax_bits) {
  __shared__ unsigned short Ut[64][72];
  const float inv2m = 0.5f / __uint_as_float(*gmax_bits);
  const int k0 = blockIdx.y * 64, n0 = blockIdx.x * 64;
  const int t = threadIdx.x;
  const int r = t >> 4, c4 = (t & 15) * 4;
#pragma unroll
  for (int rr = 0; rr < 4; ++rr) {
    int row = rr * 16 + r;
    float4 f = *(const float4*)(w + (size_t)(k0 + row) * N + n0 + c4);
    float fv[4] = {f.x, f.y, f.z, f.w};
#pragma unroll
    for (int j = 0; j < 4; ++j) {
      float tq = tanhf(fv[j]) * inv2m + 0.5f;
      float u = 2.0f * rintf(tq * 255.0f) - 255.0f;
      Ut[c4 + j][row] = f2h(u);
    }
  }
  __syncthreads();
#pragma unroll
  for (int rep = 0; rep < 2; ++rep) {
    int c = t + rep * 256;
    int n = c >> 3, slot = c & 7;
    short8 v = *(const short8*)&Ut[n][slot * 8];
    *(short8*)(ut + (size_t)(n0 + n) * K + k0 + slot * 8) = v;
  }
}

// ---------------- x -> fp16 (once) ----------------
__global__ __launch_bounds__(256) void k_xhalf(
    const float* __restrict__ x, unsigned short* __restrict__ xh, int n8) {
  int i = blockIdx.x * 256 + threadIdx.x;
  if (i >= n8) return;
  const float* src = x + (size_t)i * 8;
  float4 f0 = *(const float4*)src;
  float4 f1 = *(const float4*)(src + 4);
  float fv[8] = {f0.x, f0.y, f0.z, f0.w, f1.x, f1.y, f1.z, f1.w};
  union { short8 v; unsigned short u[8]; } o;
#pragma unroll
  for (int j = 0; j < 8; ++j) o.u[j] = f2h(fv[j]);
  *(short8*)(xh + (size_t)i * 8) = o.v;
}

// ---------------- qkv GEMM: fp16, 128x128 tile, BK=32, dbuf, 32 KB LDS --------
// 4 waves (64x64 each), 4 gl_lds/thread/iter, grid 1152 -> 4.5 blocks/CU, 5
// resident by LDS: cross-block overlap hides the per-iter vmcnt drain (m114).
// XCD swizzle bm-major: each XCD owns 8 A-panels (1.6 MB) x all 18 bn; A and the
// full B (3.5 MB) stay L2-resident. part = bn/6 block-uniform: 0=q, 1=k, 2=v.
__global__ __launch_bounds__(256, 4) void k_gemm_qkv(
    const unsigned short* __restrict__ xh, const unsigned short* __restrict__ ua,
    const float* __restrict__ bias,
    unsigned short* __restrict__ qh, unsigned short* __restrict__ kh,
    unsigned short* __restrict__ vht,
    float* __restrict__ kq, float* __restrict__ vq) {
  __shared__ __align__(16) unsigned short Ah[2][128 * 32];   // 16 KB
  __shared__ __align__(16) unsigned short Bs[2][128 * 32];   // 16 KB

  const int bid = blockIdx.x;                  // 1152, %8==0
  const int swz = (bid & 7) * 144 + (bid >> 3);
  const int bm = swz / 18, bn = swz % 18;
  const int part = bn / 6;                     // block-uniform

  const int t = threadIdx.x;
  const int w = t >> 6, lane = t & 63;
  const int wm = w >> 1, wn = w & 1;           // wave tile 64 x 64
  const int g = lane >> 4, ln = lane & 15;

  const unsigned short* Ab = xh + (size_t)bm * 128 * NXc;
  const unsigned short* Bb = ua + (size_t)bn * 128 * NXc;

  const int srow = t >> 2;                         // 0..63 (+64 for rep 1)
  const int aco  = (((t & 3) ^ ((t >> 3) & 3)) << 3);
  const int rsw  = ((g ^ ((ln >> 1) & 3)) << 3);   // read-side chunk swizzle

  f32x4 acc[4][4];
#pragma unroll
  for (int i = 0; i < 4; ++i)
#pragma unroll
    for (int j = 0; j < 4; ++j) acc[i][j] = (f32x4)(0.f);

  // prologue: stage tile 0 -> buf 0
  {
    gl_lds16(Ab + (size_t)srow * NXc + aco, &Ah[0][t * 8]);
    gl_lds16(Ab + (size_t)(srow + 64) * NXc + aco, &Ah[0][(256 + t) * 8]);
    gl_lds16(Bb + (size_t)srow * NXc + aco, &Bs[0][t * 8]);
    gl_lds16(Bb + (size_t)(srow + 64) * NXc + aco, &Bs[0][(256 + t) * 8]);
  }

  for (int tk = 0; tk < 24; ++tk) {
    __syncthreads();               // drains stage(tk); prior tile's reads done
    const int cur = tk & 1;
    if (tk + 1 < 24) {
      const int nb = cur ^ 1;
      const int k0 = (tk + 1) * 32;
      gl_lds16(Ab + (size_t)srow * NXc + k0 + aco, &Ah[nb][t * 8]);
      gl_lds16(Ab + (size_t)(srow + 64) * NXc + k0 + aco, &Ah[nb][(256 + t) * 8]);
      gl_lds16(Bb + (size_t)srow * NXc + k0 + aco, &Bs[nb][t * 8]);
      gl_lds16(Bb + (size_t)(srow + 64) * NXc + k0 + aco, &Bs[nb][(256 + t) * 8]);
    }

    half8 bfrag[4];
#pragma unroll
    for (int nf = 0; nf < 4; ++nf)
      bfrag[nf] = *(const half8*)&Bs[cur][(wn * 64 + nf * 16 + ln) * 32 + rsw];
#pragma unroll
    for (int mf = 0; mf < 4; ++mf) {
      half8 ah = *(const half8*)&Ah[cur][(wm * 64 + mf * 16 + ln) * 32 + rsw];
#pragma unroll
      for (int nf = 0; nf < 4; ++nf)
        acc[mf][nf] = __builtin_amdgcn_mfma_f32_16x16x32_f16(ah, bfrag[nf], acc[mf][nf], 0, 0, 0);
    }
  }

  const float inv255 = 1.0f / 255.0f;
#pragma unroll
  for (int mf = 0; mf < 4; ++mf) {
    int row0 = bm * 128 + wm * 64 + mf * 16 + g * 4;
#pragma unroll
    for (int nf = 0; nf < 4; ++nf) {
      int col = bn * 128 + wn * 64 + nf * 16 + ln;
      float bv = bias[col];
      int ff = col - part * NXc;
      int h = ff >> 6, d = ff & 63;
#pragma unroll
      for (int r = 0; r < 4; ++r) {
        float x = acc[mf][nf][r] * inv255 + bv;
        int row = row0 + r;
        int b = row >> 10, s = row & 1023;
        float y255 = rintf(fminf(fmaxf(x, 0.f), 1.f) * 255.0f);
        unsigned short yh = f2h(y255);       // exact fp16 integer
        size_t dst = (((size_t)b * H_ + h) * S_ + s) * HDc + d;
        if (part == 0) {
          qh[dst] = yh;
        } else if (part == 1) {
          kq[dst] = y255 * inv255;
          kh[dst] = yh;
        } else {
          vq[dst] = y255 * inv255;
          vht[(((size_t)b * H_ + h) * HDc + d) * S_ + s] = yh;   // transposed
        }
      }
    }
  }
}

// ---------------- proj GEMM: fp16, 64x128 tile, BK=32, dbuf, 24 KB LDS --------
// grid 768 (128 bm x 6 bn) -> 3 blocks/CU, 6 resident by LDS. Wave tile 32x64.
__global__ __launch_bounds__(256, 4) void k_gemm_proj(
    const unsigned short* __restrict__ ahf, const unsigned short* __restrict__ up,
    const float* __restrict__ bias, float* __restrict__ Cout) {
  __shared__ __align__(16) unsigned short Ah[2][64 * 32];    // 8 KB
  __shared__ __align__(16) unsigned short Bs[2][128 * 32];   // 16 KB

  const int bid = blockIdx.x;                  // 768, %8==0
  const int swz = (bid & 7) * 96 + (bid >> 3);
  const int bm = swz / 6, bn = swz % 6;

  const int t = threadIdx.x;
  const int w = t >> 6, lane = t & 63;
  const int wm = w >> 1, wn = w & 1;           // wave tile 32 x 64
  const int g = lane >> 4, ln = lane & 15;

  const unsigned short* Ab = ahf + (size_t)bm * 64 * NXc;
  const unsigned short* Bb = up + (size_t)bn * 128 * NXc;

  const int srow = t >> 2;
  const int aco  = (((t & 3) ^ ((t >> 3) & 3)) << 3);
  const int rsw  = ((g ^ ((ln >> 1) & 3)) << 3);

  f32x4 acc[2][4];
#pragma unroll
  for (int i = 0; i < 2; ++i)
#pragma unroll
    for (int j = 0; j < 4; ++j) acc[i][j] = (f32x4)(0.f);

  {
    gl_lds16(Ab + (size_t)srow * NXc + aco, &Ah[0][t * 8]);
    gl_lds16(Bb + (size_t)srow * NXc + aco, &Bs[0][t * 8]);
    gl_lds16(Bb + (size_t)(srow + 64) * NXc + aco, &Bs[0][(256 + t) * 8]);
  }

  for (int tk = 0; tk < 24; ++tk) {
    __syncthreads();
    const int cur = tk & 1;
    if (tk + 1 < 24) {
      const int nb = cur ^ 1;
      const int k0 = (tk + 1) * 32;
      gl_lds16(Ab + (size_t)srow * NXc + k0 + aco, &Ah[nb][t * 8]);
      gl_lds16(Bb + (size_t)srow * NXc + k0 + aco, &Bs[nb][t * 8]);
      gl_lds16(Bb + (size_t)(srow + 64) * NXc + k0 + aco, &Bs[nb][(256 + t) * 8]);
    }

    half8 bfrag[4];
#pragma unroll
    for (int nf = 0; nf < 4; ++nf)
      bfrag[nf] = *(const half8*)&Bs[cur][(wn * 64 + nf * 16 + ln) * 32 + rsw];
#pragma unroll
    for (int mf = 0; mf < 2; ++mf) {
      half8 ah = *(const half8*)&Ah[cur][(wm * 32 + mf * 16 + ln) * 32 + rsw];
#pragma unroll
      for (int nf = 0; nf < 4; ++nf)
        acc[mf][nf] = __builtin_amdgcn_mfma_f32_16x16x32_f16(ah, bfrag[nf], acc[mf][nf], 0, 0, 0);
    }
  }

  const float inv255 = 1.0f / 255.0f;
#pragma unroll
  for (int mf = 0; mf < 2; ++mf) {
    int row0 = bm * 64 + wm * 32 + mf * 16 + g * 4;
#pragma unroll
    for (int nf = 0; nf < 4; ++nf) {
      int col = bn * 128 + wn * 64 + nf * 16 + ln;
      float bv = bias[col];
#pragma unroll
      for (int r = 0; r < 4; ++r)
        Cout[(size_t)(row0 + r) * NXc + col] = acc[mf][nf][r] * inv255 + bv;
    }
  }
}

// ---------------- MFMA causal flash attention (fp16, paired q-blocks) ---------
// grid (8, H, B), 256 thr (4 waves x 16 q-rows). WG p handles q-blocks {p, 15-p}
// -> exactly 17 kv-tiles per WG. q,k,v fp16 integers: QK^T exact (sums < 2^23).
// P fp16 (2^-11). V read from pre-transposed vht.
__global__ __launch_bounds__(256) void k_attn_pair(
    const unsigned short* __restrict__ qh, const unsigned short* __restrict__ kh,
    const unsigned short* __restrict__ vht, unsigned short* __restrict__ ahf) {
  __shared__ __align__(16) unsigned short Ks[64 * 64];      // [kv][d] ^ ((kv&7)<<3)
  __shared__ __align__(16) unsigned short Vt[64 * 64];      // [d][kv] ^ ((d&7)<<3)
  __shared__ __align__(16) unsigned short Pp[4 * 16 * 64];  // per-wave [q][kv] ^ ((q&7)<<3)

  const int p = blockIdx.x, h = blockIdx.y, b = blockIdx.z;
  const size_t hoff = ((size_t)(b * H_ + h)) * S_ * HDc;
  const unsigned short* qhp = qh + hoff;
  const unsigned short* khp = kh + hoff;
  const unsigned short* vhp = vht + hoff;

  const int t = threadIdx.x;
  const int w = t >> 6, lane = t & 63;
  const int g = lane >> 4, ln = lane & 15;

  const float SCALE = 1.0f / (255.0f * 255.0f * 8.0f);

  for (int ph = 0; ph < 2; ++ph) {
    const int iq = ph ? 15 - p : p;

    const unsigned short* qr = qhp + (size_t)(iq * 64 + w * 16 + ln) * HDc;
    half8 qfrag[2];
    qfrag[0] = *(const half8*)(qr + g * 8);
    qfrag[1] = *(const half8*)(qr + 32 + g * 8);

    float m[4], l[4];
    f32x4 accO[4];
#pragma unroll
    for (int r = 0; r < 4; ++r) { m[r] = -1e30f; l[r] = 0.f; }
#pragma unroll
    for (int nf = 0; nf < 4; ++nf) accO[nf] = (f32x4)(0.f);

    for (int jb = 0; jb <= iq; ++jb) {
      __syncthreads();   // previous tile's LDS reads complete
#pragma unroll
      for (int rep = 0; rep < 2; ++rep) {
        int e = t + rep * 256;
        int row = e >> 3, slot = e & 7;
        short8 kk = *(const short8*)(khp + (size_t)(jb * 64 + row) * HDc + slot * 8);
        *(short8*)&Ks[row * 64 + ((slot * 8) ^ ((row & 7) << 3))] = kk;
        short8 vv = *(const short8*)(vhp + (size_t)row * S_ + jb * 64 + slot * 8);
        *(short8*)&Vt[row * 64 + ((slot * 8) ^ ((row & 7) << 3))] = vv;
      }
      __syncthreads();

      // QK^T (exact integer)
      f32x4 accS[4];
#pragma unroll
      for (int nf = 0; nf < 4; ++nf) accS[nf] = (f32x4)(0.f);
#pragma unroll
      for (int ks = 0; ks < 2; ++ks)
#pragma unroll
        for (int nf = 0; nf < 4; ++nf) {
          int kvr = nf * 16 + ln;
          half8 bk = *(const half8*)&Ks[kvr * 64 + ((ks * 32 + g * 8) ^ ((kvr & 7) << 3))];
          accS[nf] = __builtin_amdgcn_mfma_f32_16x16x32_f16(qfrag[ks], bk, accS[nf], 0, 0, 0);
        }

      // scale + causal mask (rows g*4+r, cols nf*16+ln)
      float sv[4][4];
      if (jb == iq) {
        const int grow = iq * 64 + w * 16 + g * 4;
        const int gcol = jb * 64 + ln;
#pragma unroll
        for (int nf = 0; nf < 4; ++nf)
#pragma unroll
          for (int r = 0; r < 4; ++r)
            sv[nf][r] = (gcol + nf * 16 > grow + r) ? -1e30f : accS[nf][r] * SCALE;
      } else {
#pragma unroll
        for (int nf = 0; nf < 4; ++nf)
#pragma unroll
          for (int r = 0; r < 4; ++r) sv[nf][r] = accS[nf][r] * SCALE;
      }

      // online softmax (rows g*4+r shared by the 16 ln-lanes)
      float mt[4];
#pragma unroll
      for (int r = 0; r < 4; ++r)
        mt[r] = fmaxf(fmaxf(sv[0][r], sv[1][r]), fmaxf(sv[2][r], sv[3][r]));
#pragma unroll
      for (int off = 1; off < 16; off <<= 1)
#pragma unroll
        for (int r = 0; r < 4; ++r) mt[r] = fmaxf(mt[r], __shfl_xor(mt[r], off));

      float pr[4][4], rs[4];
#pragma unroll
      for (int r = 0; r < 4; ++r) {
        float mn = fmaxf(m[r], mt[r]);
        float corr = __expf(m[r] - mn);
        m[r] = mn;
        l[r] *= corr;
#pragma unroll
        for (int nf = 0; nf < 4; ++nf) accO[nf][r] *= corr;
        float sum = 0.f;
#pragma unroll
        for (int nf = 0; nf < 4; ++nf) {
          float pv = __expf(sv[nf][r] - mn);
          pr[nf][r] = pv;
          sum += pv;
        }
        rs[r] = sum;
      }
#pragma unroll
      for (int off = 1; off < 16; off <<= 1)
#pragma unroll
        for (int r = 0; r < 4; ++r) rs[r] += __shfl_xor(rs[r], off);
#pragma unroll
      for (int r = 0; r < 4; ++r) l[r] += rs[r];

      // P -> LDS (fp16, within-wave round trip, no barrier)
#pragma unroll
      for (int nf = 0; nf < 4; ++nf)
#pragma unroll
        for (int r = 0; r < 4; ++r) {
          int prow = g * 4 + r;
          Pp[w * 1024 + prow * 64 + ((nf * 16 + ln) ^ ((prow & 7) << 3))] = f2h(pr[nf][r]);
        }

      // PV: accO[nf] += P(16x32) * V(32x16)
#pragma unroll
      for (int ks = 0; ks < 2; ++ks) {
        half8 pa = *(const half8*)&Pp[w * 1024 + ln * 64 + ((ks * 32 + g * 8) ^ ((ln & 7) << 3))];
#pragma unroll
        for (int nf = 0; nf < 4; ++nf) {
          int d = nf * 16 + ln;
          half8 bv = *(const half8*)&Vt[d * 64 + ((ks * 32 + g * 8) ^ ((d & 7) << 3))];
          accO[nf] = __builtin_amdgcn_mfma_f32_16x16x32_f16(pa, bv, accO[nf], 0, 0, 0);
        }
      }
    }

    // write attn-out fp16 [B,S,NX]; V was integer-scaled by 255
#pragma unroll
    for (int r = 0; r < 4; ++r) {
      float inv = 1.0f / (255.0f * l[r]);
      size_t row = (size_t)b * S_ + iq * 64 + w * 16 + g * 4 + r;
#pragma unroll
      for (int nf = 0; nf < 4; ++nf)
        ahf[row * NXc + h * HDc + nf * 16 + ln] = f2h(accO[nf][r] * inv);
    }
  }
}

// ---------------- host launcher ----------------
extern "C" void kernel_launch(void* const* d_in, const int* in_sizes, int n_in,
                              void* d_out, int out_size, void* d_ws, size_t ws_size,
                              hipStream_t stream) {
  const float* x      = (const float*)d_in[0];
  const float* W_attn = (const float*)d_in[1];
  const float* b_attn = (const float*)d_in[2];
  const float* W_proj = (const float*)d_in[3];
  const float* b_proj = (const float*)d_in[4];

  float* out = (float*)d_out;
  float* ws  = (float*)d_ws;
  if (ws_size < WS_FLOATS_NEEDED * sizeof(float)) return;

  float* a_out = out;                               // [B,S,NX]
  float* k_out = out + (size_t)M_ * NXc;            // present[0] = k  [B,H,S,hd]
  float* v_out = k_out + (size_t)M_ * NXc;          // present[1] = v

  unsigned short* ua  = (unsigned short*)(ws + UA_OFF_F);
  unsigned short* up  = (unsigned short*)(ws + UP_OFF_F);
  unsigned short* qh  = (unsigned short*)(ws + QH_OFF_F);
  unsigned short* kh  = (unsigned short*)(ws + KH_OFF_F);
  unsigned short* vht = (unsigned short*)(ws + VHT_OFF_F);
  unsigned short* ahf = (unsigned short*)(ws + AHF_OFF_F);
  unsigned int* sc = (unsigned int*)(ws + SC_OFF);

  // region reuse: xh lives in ahf's slot (attn writes ahf only AFTER qkv consumed xh)
  unsigned short* xh = ahf;

  hipMemsetAsync(sc, 0, 2 * sizeof(unsigned int), stream);

  k_maxtanh2<<<dim3(128, 2), 256, 0, stream>>>(W_attn, W_proj, sc);

  k_quantw_t<<<dim3(NQKV / 64, NXc / 64), 256, 0, stream>>>(W_attn, ua, NXc, NQKV, sc);
  k_quantw_t<<<dim3(NXc / 64, NXc / 64), 256, 0, stream>>>(W_proj, up, NXc, NXc, sc + 1);

  // x -> fp16 (once)
  k_xhalf<<<(M_ * NXc / 8 + 255) / 256, 256, 0, stream>>>(x, xh, M_ * NXc / 8);

  // qkv = x @ wq_attn + b_attn (fp16 MFMA); emits fp16 q,k,v^T + fp32 present
  k_gemm_qkv<<<(NQKV / 128) * (M_ / 128), 256, 0, stream>>>(
      xh, ua, b_attn, qh, kh, vht, k_out, v_out);

  // causal attention (paired q-blocks, fp16) — overwrites xh region with ahf
  k_attn_pair<<<dim3(8, H_, B_), 256, 0, stream>>>(qh, kh, vht, ahf);

  // a = attn_out @ wq_proj + b_proj (fp16 MFMA)
  k_gemm_proj<<<(NXc / 128) * (M_ / 64), 256, 0, stream>>>(ahf, up, b_proj, a_out);
}

// Round 10
// 186.631 us; speedup vs baseline: 1.1372x; 1.0219x over previous
//
#include <hip/hip_runtime.h>
#include <math.h>

#define B_   8
#define S_   1024
#define NXc  768
#define H_   12
#define HDc  64
#define M_   (B_*S_)        // 8192
#define NQKV (3*NXc)        // 2304

typedef __attribute__((ext_vector_type(8))) short short8;
typedef __attribute__((ext_vector_type(8))) _Float16 half8;
typedef __attribute__((ext_vector_type(4))) float f32x4;

__device__ inline unsigned short f2h(float f) {
  union { _Float16 h; unsigned short u; } c;
  c.h = (_Float16)f;                 // RNE
  return c.u;
}

__device__ inline void gl_lds16(const unsigned short* g, unsigned short* l) {
  __builtin_amdgcn_global_load_lds(
      (const __attribute__((address_space(1))) void*)g,
      (__attribute__((address_space(3))) void*)l, 16, 0, 0);
}

// ---- workspace layout (floats) ----
static const size_t UA_OFF_F  = 0;                                   // fp16 Ut attn [NQKV][NXc]
static const size_t UA_F_CNT  = ((size_t)NQKV * NXc + 1) / 2;
static const size_t UP_OFF_F  = UA_OFF_F + UA_F_CNT;                 // fp16 Ut proj [NXc][NXc]
static const size_t UP_F_CNT  = ((size_t)NXc * NXc + 1) / 2;
static const size_t QH_OFF_F  = UP_OFF_F + UP_F_CNT;                 // fp16 int q [B,H,S,64]
static const size_t HALF_CNT  = ((size_t)M_ * NXc + 1) / 2;
static const size_t KH_OFF_F  = QH_OFF_F + HALF_CNT;                 // fp16 int k [B,H,S,64]
static const size_t VHT_OFF_F = KH_OFF_F + HALF_CNT;                 // fp16 int v^T [B,H,64,S]
static const size_t AHF_OFF_F = VHT_OFF_F + HALF_CNT;                // fp16 attn out (xh earlier)
static const size_t SC_OFF    = AHF_OFF_F + HALF_CNT;
static const size_t WS_FLOATS_NEEDED = SC_OFF + 2;

// ---------------- max |tanh(w)| reduction ----------------
__global__ void k_maxtanh2(const float* __restrict__ wa, const float* __restrict__ wp,
                           unsigned int* __restrict__ out) {
  const int which = blockIdx.y;
  const float* w = which ? wp : wa;
  const int n = which ? (NXc * NXc) : (NXc * NQKV);
  float mx = 0.f;
  for (int i = blockIdx.x * blockDim.x + threadIdx.x; i < n;
       i += gridDim.x * blockDim.x)
    mx = fmaxf(mx, fabsf(tanhf(w[i])));
#pragma unroll
  for (int off = 32; off > 0; off >>= 1)
    mx = fmaxf(mx, __shfl_xor(mx, off));
  if ((threadIdx.x & 63) == 0)
    atomicMax(out + which, __float_as_uint(mx));
}

// ---------------- weight quant -> transposed exact-fp16 integer weights ------
__global__ __launch_bounds__(256) void k_quantw_t(
    const float* __restrict__ w, unsigned short* __restrict__ ut,
    int K, int N, const unsigned int* __restrict__ gmax_bits) {
  __shared__ unsigned short Ut[64][72];
  const float inv2m = 0.5f / __uint_as_float(*gmax_bits);
  const int k0 = blockIdx.y * 64, n0 = blockIdx.x * 64;
  const int t = threadIdx.x;
  const int r = t >> 4, c4 = (t & 15) * 4;
#pragma unroll
  for (int rr = 0; rr < 4; ++rr) {
    int row = rr * 16 + r;
    float4 f = *(const float4*)(w + (size_t)(k0 + row) * N + n0 + c4);
    float fv[4] = {f.x, f.y, f.z, f.w};
#pragma unroll
    for (int j = 0; j < 4; ++j) {
      float tq = tanhf(fv[j]) * inv2m + 0.5f;
      float u = 2.0f * rintf(tq * 255.0f) - 255.0f;
      Ut[c4 + j][row] = f2h(u);
    }
  }
  __syncthreads();
#pragma unroll
  for (int rep = 0; rep < 2; ++rep) {
    int c = t + rep * 256;
    int n = c >> 3, slot = c & 7;
    short8 v = *(const short8*)&Ut[n][slot * 8];
    *(short8*)(ut + (size_t)(n0 + n) * K + k0 + slot * 8) = v;
  }
}

// ---------------- x -> fp16 (once) ----------------
__global__ __launch_bounds__(256) void k_xhalf(
    const float* __restrict__ x, unsigned short* __restrict__ xh, int n8) {
  int i = blockIdx.x * 256 + threadIdx.x;
  if (i >= n8) return;
  const float* src = x + (size_t)i * 8;
  float4 f0 = *(const float4*)src;
  float4 f1 = *(const float4*)(src + 4);
  float fv[8] = {f0.x, f0.y, f0.z, f0.w, f1.x, f1.y, f1.z, f1.w};
  union { short8 v; unsigned short u[8]; } o;
#pragma unroll
  for (int j = 0; j < 8; ++j) o.u[j] = f2h(fv[j]);
  *(short8*)(xh + (size_t)i * 8) = o.v;
}

// ---------------- GEMM: 128x128, BK=32, 3-stage counted-vmcnt pipeline -------
// Per wave per stage: 4 gl_lds (1 vmcnt each). 2 stages in flight -> wait
// vmcnt(4) retires exactly the stage about to be consumed; never drains to 0
// in the main loop (T4). Raw s_barrier + sched_barrier(0) per rule #18.
// Buffer-overwrite hazard: STAGE(tk+2) hits buf[(tk-1)%3], whose COMPUTE(tk-1)
// finished in every wave before this iteration's barrier.
// EPI 1: qkv epilogue (act-quant scatter, part = bn/6). EPI 0: plain fp32.
template <int EPI>
__global__ __launch_bounds__(256, 3) void k_gemm3(
    const unsigned short* __restrict__ Ag, const unsigned short* __restrict__ Ug,
    const float* __restrict__ bias, float* __restrict__ Cout,
    unsigned short* __restrict__ qh, unsigned short* __restrict__ kh,
    unsigned short* __restrict__ vht, float* __restrict__ kq, float* __restrict__ vq,
    int nbn) {
  __shared__ __align__(16) unsigned short Ah[3][128 * 32];   // 24 KB
  __shared__ __align__(16) unsigned short Bs[3][128 * 32];   // 24 KB

  const int bid = blockIdx.x;
  const int cpx = gridDim.x >> 3;              // grid % 8 == 0
  const int swz = (bid & 7) * cpx + (bid >> 3);
  const int bm = swz / nbn, bn = swz % nbn;
  const int part = (EPI == 1) ? (bn / 6) : 0;  // block-uniform

  const int t = threadIdx.x;
  const int w = t >> 6, lane = t & 63;
  const int wm = w >> 1, wn = w & 1;           // 2x2 waves, 64x64 each
  const int g = lane >> 4, ln = lane & 15;

  const unsigned short* Ab = Ag + (size_t)bm * 128 * NXc;
  const unsigned short* Bb = Ug + (size_t)bn * 128 * NXc;

  const int srow = t >> 2;                         // 0..63 (+64 rep1)
  const int aco  = (((t & 3) ^ ((t >> 3) & 3)) << 3);
  const int rsw  = ((g ^ ((ln >> 1) & 3)) << 3);   // read-side chunk swizzle

  f32x4 acc[4][4];
#pragma unroll
  for (int i = 0; i < 4; ++i)
#pragma unroll
    for (int j = 0; j < 4; ++j) acc[i][j] = (f32x4)(0.f);

  auto STAGE = [&](int tk, int buf) {
    const int k0 = tk * 32;
    gl_lds16(Ab + (size_t)srow * NXc + k0 + aco, &Ah[buf][t * 8]);
    gl_lds16(Ab + (size_t)(srow + 64) * NXc + k0 + aco, &Ah[buf][(256 + t) * 8]);
    gl_lds16(Bb + (size_t)srow * NXc + k0 + aco, &Bs[buf][t * 8]);
    gl_lds16(Bb + (size_t)(srow + 64) * NXc + k0 + aco, &Bs[buf][(256 + t) * 8]);
  };
  auto COMPUTE = [&](int buf) {
    half8 bfrag[4];
#pragma unroll
    for (int nf = 0; nf < 4; ++nf)
      bfrag[nf] = *(const half8*)&Bs[buf][(wn * 64 + nf * 16 + ln) * 32 + rsw];
#pragma unroll
    for (int mf = 0; mf < 4; ++mf) {
      half8 ah = *(const half8*)&Ah[buf][(wm * 64 + mf * 16 + ln) * 32 + rsw];
#pragma unroll
      for (int nf = 0; nf < 4; ++nf)
        acc[mf][nf] = __builtin_amdgcn_mfma_f32_16x16x32_f16(ah, bfrag[nf], acc[mf][nf], 0, 0, 0);
    }
  };

  STAGE(0, 0);
  STAGE(1, 1);
  for (int tk = 0; tk < 22; ++tk) {            // 24 K-steps total
    asm volatile("s_waitcnt vmcnt(4)" ::: "memory");
    __builtin_amdgcn_s_barrier();
    __builtin_amdgcn_sched_barrier(0);
    STAGE(tk + 2, (tk + 2) % 3);
    COMPUTE(tk % 3);
  }
  asm volatile("s_waitcnt vmcnt(4)" ::: "memory");
  __builtin_amdgcn_s_barrier();
  __builtin_amdgcn_sched_barrier(0);
  COMPUTE(22 % 3);
  asm volatile("s_waitcnt vmcnt(0)" ::: "memory");
  __builtin_amdgcn_s_barrier();
  __builtin_amdgcn_sched_barrier(0);
  COMPUTE(23 % 3);

  const float inv255 = 1.0f / 255.0f;
#pragma unroll
  for (int mf = 0; mf < 4; ++mf) {
    int row0 = bm * 128 + wm * 64 + mf * 16 + g * 4;
#pragma unroll
    for (int nf = 0; nf < 4; ++nf) {
      int col = bn * 128 + wn * 64 + nf * 16 + ln;
      float bv = bias[col];
      int ff = col - part * NXc;
      int h = ff >> 6, d = ff & 63;
#pragma unroll
      for (int r = 0; r < 4; ++r) {
        float x = acc[mf][nf][r] * inv255 + bv;
        int row = row0 + r;
        if (EPI == 0) {
          Cout[(size_t)row * NXc + col] = x;
        } else {
          int b = row >> 10, s = row & 1023;
          float y255 = rintf(fminf(fmaxf(x, 0.f), 1.f) * 255.0f);
          unsigned short yh = f2h(y255);       // exact fp16 integer
          size_t dst = (((size_t)b * H_ + h) * S_ + s) * HDc + d;
          if (part == 0) {
            qh[dst] = yh;
          } else if (part == 1) {
            kq[dst] = y255 * inv255;
            kh[dst] = yh;
          } else {
            vq[dst] = y255 * inv255;
            vht[(((size_t)b * H_ + h) * HDc + d) * S_ + s] = yh;   // transposed
          }
        }
      }
    }
  }
}

// ---------------- MFMA causal flash attention (fp16, flattened pair) ----------
// grid (8, H, B), 256 thr. WG p does q-blocks {p, 15-p} as ONE flat 17-tile loop
// with dbuf K/V staged via gl_lds (pre-swizzled global source), single barrier
// per tile; loads hide under the previous tile's QK^T+softmax+PV.
__global__ __launch_bounds__(256) void k_attn_pair(
    const unsigned short* __restrict__ qh, const unsigned short* __restrict__ kh,
    const unsigned short* __restrict__ vht, unsigned short* __restrict__ ahf) {
  __shared__ __align__(16) unsigned short Ks[2][64 * 64];   // [kv][d]^((kv&7)<<3)
  __shared__ __align__(16) unsigned short Vt[2][64 * 64];   // [d][kv]^((d&7)<<3)
  __shared__ __align__(16) unsigned short Pp[4 * 16 * 64];  // per-wave P

  const int p = blockIdx.x, h = blockIdx.y, b = blockIdx.z;
  const size_t hoff = ((size_t)(b * H_ + h)) * S_ * HDc;
  const unsigned short* qhp = qh + hoff;
  const unsigned short* khp = kh + hoff;
  const unsigned short* vhp = vht + hoff;

  const int t = threadIdx.x;
  const int w = t >> 6, lane = t & 63;
  const int g = lane >> 4, ln = lane & 15;

  // staging: LDS linear dest (wave-contiguous), swizzled global source
  const int r0 = t >> 3, c0 = (((t & 7) ^ (r0 & 7)) << 3);        // rows 0..31
  const int r1 = 32 + (t >> 3), c1 = (((t & 7) ^ (r1 & 7)) << 3); // rows 32..63

  auto STAGE = [&](int jb, int buf) {
    gl_lds16(khp + (size_t)(jb * 64 + r0) * HDc + c0, &Ks[buf][t * 8]);
    gl_lds16(khp + (size_t)(jb * 64 + r1) * HDc + c1, &Ks[buf][(256 + t) * 8]);
    gl_lds16(vhp + (size_t)r0 * S_ + jb * 64 + c0, &Vt[buf][t * 8]);
    gl_lds16(vhp + (size_t)r1 * S_ + jb * 64 + c1, &Vt[buf][(256 + t) * 8]);
  };

  const float SCALE = 1.0f / (255.0f * 255.0f * 8.0f);

  int iq = p;
  half8 qfrag[2];
  {
    const unsigned short* qr = qhp + (size_t)(iq * 64 + w * 16 + ln) * HDc;
    qfrag[0] = *(const half8*)(qr + g * 8);
    qfrag[1] = *(const half8*)(qr + 32 + g * 8);
  }

  float m[4], l[4];
  f32x4 accO[4];
#pragma unroll
  for (int r = 0; r < 4; ++r) { m[r] = -1e30f; l[r] = 0.f; }
#pragma unroll
  for (int nf = 0; nf < 4; ++nf) accO[nf] = (f32x4)(0.f);

  auto WRITEOUT = [&]() {
#pragma unroll
    for (int r = 0; r < 4; ++r) {
      float inv = 1.0f / (255.0f * l[r]);
      size_t row = (size_t)b * S_ + iq * 64 + w * 16 + g * 4 + r;
#pragma unroll
      for (int nf = 0; nf < 4; ++nf)
        ahf[row * NXc + h * HDc + nf * 16 + ln] = f2h(accO[nf][r] * inv);
    }
  };

  STAGE(0, 0);
  int jb = 0;
  for (int i = 0; i < 17; ++i) {
    const int buf = i & 1;
    __syncthreads();               // drains stage(i); prior reads of buf done
    if (i + 1 < 17) {
      int njb = (i + 1 <= p) ? (i + 1) : (i - p);
      STAGE(njb, buf ^ 1);
    }

    // QK^T (exact integer)
    f32x4 accS[4];
#pragma unroll
    for (int nf = 0; nf < 4; ++nf) accS[nf] = (f32x4)(0.f);
#pragma unroll
    for (int ks = 0; ks < 2; ++ks)
#pragma unroll
      for (int nf = 0; nf < 4; ++nf) {
        int kvr = nf * 16 + ln;
        half8 bk = *(const half8*)&Ks[buf][kvr * 64 + ((ks * 32 + g * 8) ^ ((kvr & 7) << 3))];
        accS[nf] = __builtin_amdgcn_mfma_f32_16x16x32_f16(qfrag[ks], bk, accS[nf], 0, 0, 0);
      }

    // scale + causal mask
    float sv[4][4];
    if (jb == iq) {
      const int grow = iq * 64 + w * 16 + g * 4;
      const int gcol = jb * 64 + ln;
#pragma unroll
      for (int nf = 0; nf < 4; ++nf)
#pragma unroll
        for (int r = 0; r < 4; ++r)
          sv[nf][r] = (gcol + nf * 16 > grow + r) ? -1e30f : accS[nf][r] * SCALE;
    } else {
#pragma unroll
      for (int nf = 0; nf < 4; ++nf)
#pragma unroll
        for (int r = 0; r < 4; ++r) sv[nf][r] = accS[nf][r] * SCALE;
    }

    // online softmax (rows g*4+r across 16 ln-lanes)
    float mt[4];
#pragma unroll
    for (int r = 0; r < 4; ++r)
      mt[r] = fmaxf(fmaxf(sv[0][r], sv[1][r]), fmaxf(sv[2][r], sv[3][r]));
#pragma unroll
    for (int off = 1; off < 16; off <<= 1)
#pragma unroll
      for (int r = 0; r < 4; ++r) mt[r] = fmaxf(mt[r], __shfl_xor(mt[r], off));

    float pr[4][4], rs[4];
#pragma unroll
    for (int r = 0; r < 4; ++r) {
      float mn = fmaxf(m[r], mt[r]);
      float corr = __expf(m[r] - mn);
      m[r] = mn;
      l[r] *= corr;
#pragma unroll
      for (int nf = 0; nf < 4; ++nf) accO[nf][r] *= corr;
      float sum = 0.f;
#pragma unroll
      for (int nf = 0; nf < 4; ++nf) {
        float pv = __expf(sv[nf][r] - mn);
        pr[nf][r] = pv;
        sum += pv;
      }
      rs[r] = sum;
    }
#pragma unroll
    for (int off = 1; off < 16; off <<= 1)
#pragma unroll
      for (int r = 0; r < 4; ++r) rs[r] += __shfl_xor(rs[r], off);
#pragma unroll
    for (int r = 0; r < 4; ++r) l[r] += rs[r];

    // P -> LDS (within-wave round trip)
#pragma unroll
    for (int nf = 0; nf < 4; ++nf)
#pragma unroll
      for (int r = 0; r < 4; ++r) {
        int prow = g * 4 + r;
        Pp[w * 1024 + prow * 64 + ((nf * 16 + ln) ^ ((prow & 7) << 3))] = f2h(pr[nf][r]);
      }

    // PV
#pragma unroll
    for (int ks = 0; ks < 2; ++ks) {
      half8 pa = *(const half8*)&Pp[w * 1024 + ln * 64 + ((ks * 32 + g * 8) ^ ((ln & 7) << 3))];
#pragma unroll
      for (int nf = 0; nf < 4; ++nf) {
        int d = nf * 16 + ln;
        half8 bv = *(const half8*)&Vt[buf][d * 64 + ((ks * 32 + g * 8) ^ ((d & 7) << 3))];
        accO[nf] = __builtin_amdgcn_mfma_f32_16x16x32_f16(pa, bv, accO[nf], 0, 0, 0);
      }
    }

    // phase transition / finalize
    if (i == p) {
      WRITEOUT();
#pragma unroll
      for (int r = 0; r < 4; ++r) { m[r] = -1e30f; l[r] = 0.f; }
#pragma unroll
      for (int nf = 0; nf < 4; ++nf) accO[nf] = (f32x4)(0.f);
      iq = 15 - p;
      const unsigned short* qr2 = qhp + (size_t)(iq * 64 + w * 16 + ln) * HDc;
      qfrag[0] = *(const half8*)(qr2 + g * 8);
      qfrag[1] = *(const half8*)(qr2 + 32 + g * 8);
    } else if (i == 16) {
      WRITEOUT();
    }
    jb = (i + 1 <= p) ? (i + 1) : (i - p);
  }
}

// ---------------- host launcher ----------------
extern "C" void kernel_launch(void* const* d_in, const int* in_sizes, int n_in,
                              void* d_out, int out_size, void* d_ws, size_t ws_size,
                              hipStream_t stream) {
  const float* x      = (const float*)d_in[0];
  const float* W_attn = (const float*)d_in[1];
  const float* b_attn = (const float*)d_in[2];
  const float* W_proj = (const float*)d_in[3];
  const float* b_proj = (const float*)d_in[4];

  float* out = (float*)d_out;
  float* ws  = (float*)d_ws;
  if (ws_size < WS_FLOATS_NEEDED * sizeof(float)) return;

  float* a_out = out;                               // [B,S,NX]
  float* k_out = out + (size_t)M_ * NXc;            // present[0] = k
  float* v_out = k_out + (size_t)M_ * NXc;          // present[1] = v

  unsigned short* ua  = (unsigned short*)(ws + UA_OFF_F);
  unsigned short* up  = (unsigned short*)(ws + UP_OFF_F);
  unsigned short* qh  = (unsigned short*)(ws + QH_OFF_F);
  unsigned short* kh  = (unsigned short*)(ws + KH_OFF_F);
  unsigned short* vht = (unsigned short*)(ws + VHT_OFF_F);
  unsigned short* ahf = (unsigned short*)(ws + AHF_OFF_F);
  unsigned int* sc = (unsigned int*)(ws + SC_OFF);

  unsigned short* xh = ahf;   // region reuse: attn writes ahf only after qkv read xh

  hipMemsetAsync(sc, 0, 2 * sizeof(unsigned int), stream);

  k_maxtanh2<<<dim3(128, 2), 256, 0, stream>>>(W_attn, W_proj, sc);

  k_quantw_t<<<dim3(NQKV / 64, NXc / 64), 256, 0, stream>>>(W_attn, ua, NXc, NQKV, sc);
  k_quantw_t<<<dim3(NXc / 64, NXc / 64), 256, 0, stream>>>(W_proj, up, NXc, NXc, sc + 1);

  k_xhalf<<<(M_ * NXc / 8 + 255) / 256, 256, 0, stream>>>(x, xh, M_ * NXc / 8);

  // qkv = x @ wq_attn + b_attn (fp16 MFMA, counted-vmcnt pipeline)
  k_gemm3<1><<<(NQKV / 128) * (M_ / 128), 256, 0, stream>>>(
      xh, ua, b_attn, nullptr, qh, kh, vht, k_out, v_out, NQKV / 128);

  // causal attention (flattened paired q-blocks, gl_lds dbuf staging)
  k_attn_pair<<<dim3(8, H_, B_), 256, 0, stream>>>(qh, kh, vht, ahf);

  // a = attn_out @ wq_proj + b_proj
  k_gemm3<0><<<(NXc / 128) * (M_ / 128), 256, 0, stream>>>(
      ahf, up, b_proj, a_out, nullptr, nullptr, nullptr, nullptr, nullptr, NXc / 128);
}

// Round 12
// 161.996 us; speedup vs baseline: 1.3102x; 1.1521x over previous
//
#include <hip/hip_runtime.h>
#include <math.h>

#define B_   8
#define S_   1024
#define NXc  768
#define H_   12
#define HDc  64
#define M_   (B_*S_)        // 8192
#define NQKV (3*NXc)        // 2304

typedef __attribute__((ext_vector_type(8))) short short8;
typedef __attribute__((ext_vector_type(8))) _Float16 half8;
typedef __attribute__((ext_vector_type(4))) float f32x4;

__device__ inline unsigned short f2h(float f) {
  union { _Float16 h; unsigned short u; } c;
  c.h = (_Float16)f;                 // RNE
  return c.u;
}

__device__ inline void gl_lds16(const unsigned short* g, unsigned short* l) {
  __builtin_amdgcn_global_load_lds(
      (const __attribute__((address_space(1))) void*)g,
      (__attribute__((address_space(3))) void*)l, 16, 0, 0);
}

// ---- workspace layout (floats) ----
static const size_t UA_OFF_F  = 0;                                   // fp16 Ut attn [NQKV][NXc]
static const size_t UA_F_CNT  = ((size_t)NQKV * NXc + 1) / 2;
static const size_t UP_OFF_F  = UA_OFF_F + UA_F_CNT;                 // fp16 Ut proj [NXc][NXc]
static const size_t UP_F_CNT  = ((size_t)NXc * NXc + 1) / 2;
static const size_t QH_OFF_F  = UP_OFF_F + UP_F_CNT;                 // fp16 int q [B,H,S,64]
static const size_t HALF_CNT  = ((size_t)M_ * NXc + 1) / 2;
static const size_t KH_OFF_F  = QH_OFF_F + HALF_CNT;                 // fp16 int k [B,H,S,64]
static const size_t VHT_OFF_F = KH_OFF_F + HALF_CNT;                 // fp16 int v^T [B,H,64,S]
static const size_t AHF_OFF_F = VHT_OFF_F + HALF_CNT;                // fp16 attn out (xh earlier)
static const size_t SC_OFF    = AHF_OFF_F + HALF_CNT;
static const size_t WS_FLOATS_NEEDED = SC_OFF + 2;

// ---------------- max |tanh(w)| reduction ----------------
__global__ void k_maxtanh2(const float* __restrict__ wa, const float* __restrict__ wp,
                           unsigned int* __restrict__ out) {
  const int which = blockIdx.y;
  const float* w = which ? wp : wa;
  const int n = which ? (NXc * NXc) : (NXc * NQKV);
  float mx = 0.f;
  for (int i = blockIdx.x * blockDim.x + threadIdx.x; i < n;
       i += gridDim.x * blockDim.x)
    mx = fmaxf(mx, fabsf(tanhf(w[i])));
#pragma unroll
  for (int off = 32; off > 0; off >>= 1)
    mx = fmaxf(mx, __shfl_xor(mx, off));
  if ((threadIdx.x & 63) == 0)
    atomicMax(out + which, __float_as_uint(mx));
}

// ---------------- weight quant -> transposed exact-fp16 integer weights ------
__global__ __launch_bounds__(256) void k_quantw_t(
    const float* __restrict__ w, unsigned short* __restrict__ ut,
    int K, int N, const unsigned int* __restrict__ gmax_bits) {
  __shared__ unsigned short Ut[64][72];
  const float inv2m = 0.5f / __uint_as_float(*gmax_bits);
  const int k0 = blockIdx.y * 64, n0 = blockIdx.x * 64;
  const int t = threadIdx.x;
  const int r = t >> 4, c4 = (t & 15) * 4;
#pragma unroll
  for (int rr = 0; rr < 4; ++rr) {
    int row = rr * 16 + r;
    float4 f = *(const float4*)(w + (size_t)(k0 + row) * N + n0 + c4);
    float fv[4] = {f.x, f.y, f.z, f.w};
#pragma unroll
    for (int j = 0; j < 4; ++j) {
      float tq = tanhf(fv[j]) * inv2m + 0.5f;
      float u = 2.0f * rintf(tq * 255.0f) - 255.0f;
      Ut[c4 + j][row] = f2h(u);
    }
  }
  __syncthreads();
#pragma unroll
  for (int rep = 0; rep < 2; ++rep) {
    int c = t + rep * 256;
    int n = c >> 3, slot = c & 7;
    short8 v = *(const short8*)&Ut[n][slot * 8];
    *(short8*)(ut + (size_t)(n0 + n) * K + k0 + slot * 8) = v;
  }
}

// ---------------- x -> fp16 (once) ----------------
__global__ __launch_bounds__(256) void k_xhalf(
    const float* __restrict__ x, unsigned short* __restrict__ xh, int n8) {
  int i = blockIdx.x * 256 + threadIdx.x;
  if (i >= n8) return;
  const float* src = x + (size_t)i * 8;
  float4 f0 = *(const float4*)src;
  float4 f1 = *(const float4*)(src + 4);
  float fv[8] = {f0.x, f0.y, f0.z, f0.w, f1.x, f1.y, f1.z, f1.w};
  union { short8 v; unsigned short u[8]; } o;
#pragma unroll
  for (int j = 0; j < 8; ++j) o.u[j] = f2h(fv[j]);
  *(short8*)(xh + (size_t)i * 8) = o.v;
}

// ---------------- GEMM: 128x128, BK=32, 3-stage counted-vmcnt pipeline -------
// part=2 (v) epilogue routes the transpose through LDS T[c][s], stride 136
// shorts (272 B): every short8 read at c*136 + sc*8 is 16B-aligned (272%16==0)
// -- round 11's stride-130 misaligned 3/4 of the ds_read_b128 (the failure).
// vht then written with coalesced 16B stores (2048/block) instead of 16K
// 64-line scattered 2B stores.
template <int EPI>
__global__ __launch_bounds__(256, 3) void k_gemm3(
    const unsigned short* __restrict__ Ag, const unsigned short* __restrict__ Ug,
    const float* __restrict__ bias, float* __restrict__ Cout,
    unsigned short* __restrict__ qh, unsigned short* __restrict__ kh,
    unsigned short* __restrict__ vht, float* __restrict__ kq, float* __restrict__ vq,
    int nbn) {
  __shared__ __align__(16) unsigned short SMEM[3 * 4096 * 2];   // 48 KB
  unsigned short* Ahb3 = SMEM;                 // 3 bufs x 4096 shorts
  unsigned short* Bsb3 = SMEM + 3 * 4096;
  unsigned short* T    = SMEM;                 // aliased after final barrier: [128][136]

  const int bid = blockIdx.x;
  const int cpx = gridDim.x >> 3;              // grid % 8 == 0
  const int swz = (bid & 7) * cpx + (bid >> 3);
  const int bm = swz / nbn, bn = swz % nbn;
  const int part = (EPI == 1) ? (bn / 6) : 0;  // block-uniform

  const int t = threadIdx.x;
  const int w = t >> 6, lane = t & 63;
  const int wm = w >> 1, wn = w & 1;           // 2x2 waves, 64x64 each
  const int g = lane >> 4, ln = lane & 15;

  const unsigned short* Ab = Ag + (size_t)bm * 128 * NXc;
  const unsigned short* Bb = Ug + (size_t)bn * 128 * NXc;

  const int srow = t >> 2;                         // 0..63 (+64 rep1)
  const int aco  = (((t & 3) ^ ((t >> 3) & 3)) << 3);
  const int rsw  = ((g ^ ((ln >> 1) & 3)) << 3);   // read-side chunk swizzle

  f32x4 acc[4][4];
#pragma unroll
  for (int i = 0; i < 4; ++i)
#pragma unroll
    for (int j = 0; j < 4; ++j) acc[i][j] = (f32x4)(0.f);

  auto STAGE = [&](int tk, int buf) {
    const int k0 = tk * 32;
    unsigned short* Ah = Ahb3 + buf * 4096;
    unsigned short* Bs = Bsb3 + buf * 4096;
    gl_lds16(Ab + (size_t)srow * NXc + k0 + aco, &Ah[t * 8]);
    gl_lds16(Ab + (size_t)(srow + 64) * NXc + k0 + aco, &Ah[(256 + t) * 8]);
    gl_lds16(Bb + (size_t)srow * NXc + k0 + aco, &Bs[t * 8]);
    gl_lds16(Bb + (size_t)(srow + 64) * NXc + k0 + aco, &Bs[(256 + t) * 8]);
  };
  auto COMPUTE = [&](int buf) {
    const unsigned short* Ah = Ahb3 + buf * 4096;
    const unsigned short* Bs = Bsb3 + buf * 4096;
    half8 bfrag[4];
#pragma unroll
    for (int nf = 0; nf < 4; ++nf)
      bfrag[nf] = *(const half8*)&Bs[(wn * 64 + nf * 16 + ln) * 32 + rsw];
#pragma unroll
    for (int mf = 0; mf < 4; ++mf) {
      half8 ah = *(const half8*)&Ah[(wm * 64 + mf * 16 + ln) * 32 + rsw];
#pragma unroll
      for (int nf = 0; nf < 4; ++nf)
        acc[mf][nf] = __builtin_amdgcn_mfma_f32_16x16x32_f16(ah, bfrag[nf], acc[mf][nf], 0, 0, 0);
    }
  };

  STAGE(0, 0);
  STAGE(1, 1);
  for (int tk = 0; tk < 22; ++tk) {            // 24 K-steps total
    asm volatile("s_waitcnt vmcnt(4)" ::: "memory");
    __builtin_amdgcn_s_barrier();
    __builtin_amdgcn_sched_barrier(0);
    STAGE(tk + 2, (tk + 2) % 3);
    COMPUTE(tk % 3);
  }
  asm volatile("s_waitcnt vmcnt(4)" ::: "memory");
  __builtin_amdgcn_s_barrier();
  __builtin_amdgcn_sched_barrier(0);
  COMPUTE(22 % 3);
  asm volatile("s_waitcnt vmcnt(0)" ::: "memory");
  __builtin_amdgcn_s_barrier();
  __builtin_amdgcn_sched_barrier(0);
  COMPUTE(23 % 3);

  const float inv255 = 1.0f / 255.0f;
  if (EPI == 1 && part == 2) {
    // v-part: vq coalesced directly; vht via LDS transpose then coalesced 16B.
    __syncthreads();                            // pipeline LDS reads complete
#pragma unroll
    for (int mf = 0; mf < 4; ++mf) {
      int row0 = bm * 128 + wm * 64 + mf * 16 + g * 4;
#pragma unroll
      for (int nf = 0; nf < 4; ++nf) {
        int col = bn * 128 + wn * 64 + nf * 16 + ln;
        float bv = bias[col];
        int ff = col - 2 * NXc;
        int h = ff >> 6, d = ff & 63;
        int c = wn * 64 + nf * 16 + ln;         // local col 0..127
#pragma unroll
        for (int r = 0; r < 4; ++r) {
          float x = acc[mf][nf][r] * inv255 + bv;
          int row = row0 + r;
          int b = row >> 10, s = row & 1023;
          float y255 = rintf(fminf(fmaxf(x, 0.f), 1.f) * 255.0f);
          vq[(((size_t)b * H_ + h) * S_ + s) * HDc + d] = y255 * inv255;
          int sl = wm * 64 + mf * 16 + g * 4 + r;   // local row 0..127
          T[c * 136 + sl] = f2h(y255);
        }
      }
    }
    __syncthreads();
    const int bB = bm >> 3;                      // batch
    const int s0 = (bm & 7) * 128;               // s base of this block
    const int h0 = (bn - 12) * 2;                // two heads per block
#pragma unroll
    for (int rep = 0; rep < 8; ++rep) {
      int idx = rep * 256 + t;                   // 2048 chunks
      int c = idx >> 4, sc = idx & 15;
      short8 v = *(const short8*)&T[c * 136 + sc * 8];   // 272B rows: aligned
      int h = h0 + (c >> 6), d = c & 63;
      *(short8*)(vht + (((size_t)bB * H_ + h) * HDc + d) * S_ + s0 + sc * 8) = v;
    }
  } else {
#pragma unroll
    for (int mf = 0; mf < 4; ++mf) {
      int row0 = bm * 128 + wm * 64 + mf * 16 + g * 4;
#pragma unroll
      for (int nf = 0; nf < 4; ++nf) {
        int col = bn * 128 + wn * 64 + nf * 16 + ln;
        float bv = bias[col];
        int ff = col - part * NXc;
        int h = ff >> 6, d = ff & 63;
#pragma unroll
        for (int r = 0; r < 4; ++r) {
          float x = acc[mf][nf][r] * inv255 + bv;
          int row = row0 + r;
          if (EPI == 0) {
            Cout[(size_t)row * NXc + col] = x;
          } else {
            int b = row >> 10, s = row & 1023;
            float y255 = rintf(fminf(fmaxf(x, 0.f), 1.f) * 255.0f);
            unsigned short yh = f2h(y255);
            size_t dst = (((size_t)b * H_ + h) * S_ + s) * HDc + d;
            if (part == 0) {
              qh[dst] = yh;
            } else {
              kq[dst] = y255 * inv255;
              kh[dst] = yh;
            }
          }
        }
      }
    }
  }
}

// ---------------- MFMA causal flash attention (fp16, flattened pair) ----------
__global__ __launch_bounds__(256) void k_attn_pair(
    const unsigned short* __restrict__ qh, const unsigned short* __restrict__ kh,
    const unsigned short* __restrict__ vht, unsigned short* __restrict__ ahf) {
  __shared__ __align__(16) unsigned short Ks[2][64 * 64];   // [kv][d]^((kv&7)<<3)
  __shared__ __align__(16) unsigned short Vt[2][64 * 64];   // [d][kv]^((d&7)<<3)
  __shared__ __align__(16) unsigned short Pp[4 * 16 * 64];  // per-wave P

  const int p = blockIdx.x, h = blockIdx.y, b = blockIdx.z;
  const size_t hoff = ((size_t)(b * H_ + h)) * S_ * HDc;
  const unsigned short* qhp = qh + hoff;
  const unsigned short* khp = kh + hoff;
  const unsigned short* vhp = vht + hoff;

  const int t = threadIdx.x;
  const int w = t >> 6, lane = t & 63;
  const int g = lane >> 4, ln = lane & 15;

  const int r0 = t >> 3, c0 = (((t & 7) ^ (r0 & 7)) << 3);
  const int r1 = 32 + (t >> 3), c1 = (((t & 7) ^ (r1 & 7)) << 3);

  auto STAGE = [&](int jb, int buf) {
    gl_lds16(khp + (size_t)(jb * 64 + r0) * HDc + c0, &Ks[buf][t * 8]);
    gl_lds16(khp + (size_t)(jb * 64 + r1) * HDc + c1, &Ks[buf][(256 + t) * 8]);
    gl_lds16(vhp + (size_t)r0 * S_ + jb * 64 + c0, &Vt[buf][t * 8]);
    gl_lds16(vhp + (size_t)r1 * S_ + jb * 64 + c1, &Vt[buf][(256 + t) * 8]);
  };

  const float SCALE = 1.0f / (255.0f * 255.0f * 8.0f);

  int iq = p;
  half8 qfrag[2];
  {
    const unsigned short* qr = qhp + (size_t)(iq * 64 + w * 16 + ln) * HDc;
    qfrag[0] = *(const half8*)(qr + g * 8);
    qfrag[1] = *(const half8*)(qr + 32 + g * 8);
  }

  float m[4], l[4];
  f32x4 accO[4];
#pragma unroll
  for (int r = 0; r < 4; ++r) { m[r] = -1e30f; l[r] = 0.f; }
#pragma unroll
  for (int nf = 0; nf < 4; ++nf) accO[nf] = (f32x4)(0.f);

  auto WRITEOUT = [&]() {
#pragma unroll
    for (int r = 0; r < 4; ++r) {
      float inv = 1.0f / (255.0f * l[r]);
      size_t row = (size_t)b * S_ + iq * 64 + w * 16 + g * 4 + r;
#pragma unroll
      for (int nf = 0; nf < 4; ++nf)
        ahf[row * NXc + h * HDc + nf * 16 + ln] = f2h(accO[nf][r] * inv);
    }
  };

  STAGE(0, 0);
  int jb = 0;
  for (int i = 0; i < 17; ++i) {
    const int buf = i & 1;
    __syncthreads();
    if (i + 1 < 17) {
      int njb = (i + 1 <= p) ? (i + 1) : (i - p);
      STAGE(njb, buf ^ 1);
    }

    f32x4 accS[4];
#pragma unroll
    for (int nf = 0; nf < 4; ++nf) accS[nf] = (f32x4)(0.f);
#pragma unroll
    for (int ks = 0; ks < 2; ++ks)
#pragma unroll
      for (int nf = 0; nf < 4; ++nf) {
        int kvr = nf * 16 + ln;
        half8 bk = *(const half8*)&Ks[buf][kvr * 64 + ((ks * 32 + g * 8) ^ ((kvr & 7) << 3))];
        accS[nf] = __builtin_amdgcn_mfma_f32_16x16x32_f16(qfrag[ks], bk, accS[nf], 0, 0, 0);
      }

    float sv[4][4];
    if (jb == iq) {
      const int grow = iq * 64 + w * 16 + g * 4;
      const int gcol = jb * 64 + ln;
#pragma unroll
      for (int nf = 0; nf < 4; ++nf)
#pragma unroll
        for (int r = 0; r < 4; ++r)
          sv[nf][r] = (gcol + nf * 16 > grow + r) ? -1e30f : accS[nf][r] * SCALE;
    } else {
#pragma unroll
      for (int nf = 0; nf < 4; ++nf)
#pragma unroll
        for (int r = 0; r < 4; ++r) sv[nf][r] = accS[nf][r] * SCALE;
    }

    float mt[4];
#pragma unroll
    for (int r = 0; r < 4; ++r)
      mt[r] = fmaxf(fmaxf(sv[0][r], sv[1][r]), fmaxf(sv[2][r], sv[3][r]));
#pragma unroll
    for (int off = 1; off < 16; off <<= 1)
#pragma unroll
      for (int r = 0; r < 4; ++r) mt[r] = fmaxf(mt[r], __shfl_xor(mt[r], off));

    float pr[4][4], rs[4];
#pragma unroll
    for (int r = 0; r < 4; ++r) {
      float mn = fmaxf(m[r], mt[r]);
      float corr = __expf(m[r] - mn);
      m[r] = mn;
      l[r] *= corr;
#pragma unroll
      for (int nf = 0; nf < 4; ++nf) accO[nf][r] *= corr;
      float sum = 0.f;
#pragma unroll
      for (int nf = 0; nf < 4; ++nf) {
        float pv = __expf(sv[nf][r] - mn);
        pr[nf][r] = pv;
        sum += pv;
      }
      rs[r] = sum;
    }
#pragma unroll
    for (int off = 1; off < 16; off <<= 1)
#pragma unroll
      for (int r = 0; r < 4; ++r) rs[r] += __shfl_xor(rs[r], off);
#pragma unroll
    for (int r = 0; r < 4; ++r) l[r] += rs[r];

#pragma unroll
    for (int nf = 0; nf < 4; ++nf)
#pragma unroll
      for (int r = 0; r < 4; ++r) {
        int prow = g * 4 + r;
        Pp[w * 1024 + prow * 64 + ((nf * 16 + ln) ^ ((prow & 7) << 3))] = f2h(pr[nf][r]);
      }

#pragma unroll
    for (int ks = 0; ks < 2; ++ks) {
      half8 pa = *(const half8*)&Pp[w * 1024 + ln * 64 + ((ks * 32 + g * 8) ^ ((ln & 7) << 3))];
#pragma unroll
      for (int nf = 0; nf < 4; ++nf) {
        int d = nf * 16 + ln;
        half8 bv = *(const half8*)&Vt[buf][d * 64 + ((ks * 32 + g * 8) ^ ((d & 7) << 3))];
        accO[nf] = __builtin_amdgcn_mfma_f32_16x16x32_f16(pa, bv, accO[nf], 0, 0, 0);
      }
    }

    if (i == p) {
      WRITEOUT();
#pragma unroll
      for (int r = 0; r < 4; ++r) { m[r] = -1e30f; l[r] = 0.f; }
#pragma unroll
      for (int nf = 0; nf < 4; ++nf) accO[nf] = (f32x4)(0.f);
      iq = 15 - p;
      const unsigned short* qr2 = qhp + (size_t)(iq * 64 + w * 16 + ln) * HDc;
      qfrag[0] = *(const half8*)(qr2 + g * 8);
      qfrag[1] = *(const half8*)(qr2 + 32 + g * 8);
    } else if (i == 16) {
      WRITEOUT();
    }
    jb = (i + 1 <= p) ? (i + 1) : (i - p);
  }
}

// ---------------- host launcher ----------------
extern "C" void kernel_launch(void* const* d_in, const int* in_sizes, int n_in,
                              void* d_out, int out_size, void* d_ws, size_t ws_size,
                              hipStream_t stream) {
  const float* x      = (const float*)d_in[0];
  const float* W_attn = (const float*)d_in[1];
  const float* b_attn = (const float*)d_in[2];
  const float* W_proj = (const float*)d_in[3];
  const float* b_proj = (const float*)d_in[4];

  float* out = (float*)d_out;
  float* ws  = (float*)d_ws;
  if (ws_size < WS_FLOATS_NEEDED * sizeof(float)) return;

  float* a_out = out;                               // [B,S,NX]
  float* k_out = out + (size_t)M_ * NXc;            // present[0] = k
  float* v_out = k_out + (size_t)M_ * NXc;          // present[1] = v

  unsigned short* ua  = (unsigned short*)(ws + UA_OFF_F);
  unsigned short* up  = (unsigned short*)(ws + UP_OFF_F);
  unsigned short* qh  = (unsigned short*)(ws + QH_OFF_F);
  unsigned short* kh  = (unsigned short*)(ws + KH_OFF_F);
  unsigned short* vht = (unsigned short*)(ws + VHT_OFF_F);
  unsigned short* ahf = (unsigned short*)(ws + AHF_OFF_F);
  unsigned int* sc = (unsigned int*)(ws + SC_OFF);

  unsigned short* xh = ahf;   // region reuse: attn writes ahf only after qkv read xh

  hipMemsetAsync(sc, 0, 2 * sizeof(unsigned int), stream);

  k_maxtanh2<<<dim3(128, 2), 256, 0, stream>>>(W_attn, W_proj, sc);

  k_quantw_t<<<dim3(NQKV / 64, NXc / 64), 256, 0, stream>>>(W_attn, ua, NXc, NQKV, sc);
  k_quantw_t<<<dim3(NXc / 64, NXc / 64), 256, 0, stream>>>(W_proj, up, NXc, NXc, sc + 1);

  k_xhalf<<<(M_ * NXc / 8 + 255) / 256, 256, 0, stream>>>(x, xh, M_ * NXc / 8);

  // qkv = x @ wq_attn + b_attn (fp16 MFMA, counted-vmcnt pipeline, LDS-transposed v)
  k_gemm3<1><<<(NQKV / 128) * (M_ / 128), 256, 0, stream>>>(
      xh, ua, b_attn, nullptr, qh, kh, vht, k_out, v_out, NQKV / 128);

  // causal attention (flattened paired q-blocks, gl_lds dbuf staging)
  k_attn_pair<<<dim3(8, H_, B_), 256, 0, stream>>>(qh, kh, vht, ahf);

  // a = attn_out @ wq_proj + b_proj
  k_gemm3<0><<<(NXc / 128) * (M_ / 128), 256, 0, stream>>>(
      ahf, up, b_proj, a_out, nullptr, nullptr, nullptr, nullptr, nullptr, NXc / 128);
}

// Round 13
// 141.828 us; speedup vs baseline: 1.4965x; 1.1422x over previous
//
#include <hip/hip_runtime.h>
#include <math.h>

#define B_   8
#define S_   1024
#define NXc  768
#define H_   12
#define HDc  64
#define M_   (B_*S_)        // 8192
#define NQKV (3*NXc)        // 2304

typedef __attribute__((ext_vector_type(8))) short short8;
typedef __attribute__((ext_vector_type(8))) _Float16 half8;
typedef __attribute__((ext_vector_type(4))) float f32x4;

__device__ inline unsigned short f2h(float f) {
  union { _Float16 h; unsigned short u; } c;
  c.h = (_Float16)f;                 // RNE
  return c.u;
}

__device__ inline void gl_lds16(const unsigned short* g, unsigned short* l) {
  __builtin_amdgcn_global_load_lds(
      (const __attribute__((address_space(1))) void*)g,
      (__attribute__((address_space(3))) void*)l, 16, 0, 0);
}

// ---- workspace layout (floats) ----
static const size_t UA_OFF_F  = 0;                                   // fp16 Ut attn [NQKV][NXc]
static const size_t UA_F_CNT  = ((size_t)NQKV * NXc + 1) / 2;
static const size_t UP_OFF_F  = UA_OFF_F + UA_F_CNT;                 // fp16 Ut proj [NXc][NXc]
static const size_t UP_F_CNT  = ((size_t)NXc * NXc + 1) / 2;
static const size_t QH_OFF_F  = UP_OFF_F + UP_F_CNT;                 // fp16 int q [B,H,S,64]
static const size_t HALF_CNT  = ((size_t)M_ * NXc + 1) / 2;
static const size_t KH_OFF_F  = QH_OFF_F + HALF_CNT;                 // fp16 int k [B,H,S,64]
static const size_t VHT_OFF_F = KH_OFF_F + HALF_CNT;                 // fp16 int v^T [B,H,64,S]
static const size_t AHF_OFF_F = VHT_OFF_F + HALF_CNT;                // fp16 attn out (xh earlier)
static const size_t SC_OFF    = AHF_OFF_F + HALF_CNT;
static const size_t WS_FLOATS_NEEDED = SC_OFF + 2;

// ---------------- max |tanh(w)| reduction ----------------
__global__ void k_maxtanh2(const float* __restrict__ wa, const float* __restrict__ wp,
                           unsigned int* __restrict__ out) {
  const int which = blockIdx.y;
  const float* w = which ? wp : wa;
  const int n = which ? (NXc * NXc) : (NXc * NQKV);
  float mx = 0.f;
  for (int i = blockIdx.x * blockDim.x + threadIdx.x; i < n;
       i += gridDim.x * blockDim.x)
    mx = fmaxf(mx, fabsf(tanhf(w[i])));
#pragma unroll
  for (int off = 32; off > 0; off >>= 1)
    mx = fmaxf(mx, __shfl_xor(mx, off));
  if ((threadIdx.x & 63) == 0)
    atomicMax(out + which, __float_as_uint(mx));
}

// ---------------- weight quant -> transposed exact-fp16 integer weights ------
__global__ __launch_bounds__(256) void k_quantw_t(
    const float* __restrict__ w, unsigned short* __restrict__ ut,
    int K, int N, const unsigned int* __restrict__ gmax_bits) {
  __shared__ unsigned short Ut[64][72];
  const float inv2m = 0.5f / __uint_as_float(*gmax_bits);
  const int k0 = blockIdx.y * 64, n0 = blockIdx.x * 64;
  const int t = threadIdx.x;
  const int r = t >> 4, c4 = (t & 15) * 4;
#pragma unroll
  for (int rr = 0; rr < 4; ++rr) {
    int row = rr * 16 + r;
    float4 f = *(const float4*)(w + (size_t)(k0 + row) * N + n0 + c4);
    float fv[4] = {f.x, f.y, f.z, f.w};
#pragma unroll
    for (int j = 0; j < 4; ++j) {
      float tq = tanhf(fv[j]) * inv2m + 0.5f;
      float u = 2.0f * rintf(tq * 255.0f) - 255.0f;
      Ut[c4 + j][row] = f2h(u);
    }
  }
  __syncthreads();
#pragma unroll
  for (int rep = 0; rep < 2; ++rep) {
    int c = t + rep * 256;
    int n = c >> 3, slot = c & 7;
    short8 v = *(const short8*)&Ut[n][slot * 8];
    *(short8*)(ut + (size_t)(n0 + n) * K + k0 + slot * 8) = v;
  }
}

// ---------------- x -> fp16 (once) ----------------
__global__ __launch_bounds__(256) void k_xhalf(
    const float* __restrict__ x, unsigned short* __restrict__ xh, int n8) {
  int i = blockIdx.x * 256 + threadIdx.x;
  if (i >= n8) return;
  const float* src = x + (size_t)i * 8;
  float4 f0 = *(const float4*)src;
  float4 f1 = *(const float4*)(src + 4);
  float fv[8] = {f0.x, f0.y, f0.z, f0.w, f1.x, f1.y, f1.z, f1.w};
  union { short8 v; unsigned short u[8]; } o;
#pragma unroll
  for (int j = 0; j < 8; ++j) o.u[j] = f2h(fv[j]);
  *(short8*)(xh + (size_t)i * 8) = o.v;
}

// ---------------- GEMM: 128x128, BK=32, 3-stage counted-vmcnt pipeline -------
// (unchanged from round 12 — vht via aligned LDS transpose, coalesced 16B stores)
template <int EPI>
__global__ __launch_bounds__(256, 3) void k_gemm3(
    const unsigned short* __restrict__ Ag, const unsigned short* __restrict__ Ug,
    const float* __restrict__ bias, float* __restrict__ Cout,
    unsigned short* __restrict__ qh, unsigned short* __restrict__ kh,
    unsigned short* __restrict__ vht, float* __restrict__ kq, float* __restrict__ vq,
    int nbn) {
  __shared__ __align__(16) unsigned short SMEM[3 * 4096 * 2];   // 48 KB
  unsigned short* Ahb3 = SMEM;
  unsigned short* Bsb3 = SMEM + 3 * 4096;
  unsigned short* T    = SMEM;                 // aliased after final barrier: [128][136]

  const int bid = blockIdx.x;
  const int cpx = gridDim.x >> 3;
  const int swz = (bid & 7) * cpx + (bid >> 3);
  const int bm = swz / nbn, bn = swz % nbn;
  const int part = (EPI == 1) ? (bn / 6) : 0;

  const int t = threadIdx.x;
  const int w = t >> 6, lane = t & 63;
  const int wm = w >> 1, wn = w & 1;
  const int g = lane >> 4, ln = lane & 15;

  const unsigned short* Ab = Ag + (size_t)bm * 128 * NXc;
  const unsigned short* Bb = Ug + (size_t)bn * 128 * NXc;

  const int srow = t >> 2;
  const int aco  = (((t & 3) ^ ((t >> 3) & 3)) << 3);
  const int rsw  = ((g ^ ((ln >> 1) & 3)) << 3);

  f32x4 acc[4][4];
#pragma unroll
  for (int i = 0; i < 4; ++i)
#pragma unroll
    for (int j = 0; j < 4; ++j) acc[i][j] = (f32x4)(0.f);

  auto STAGE = [&](int tk, int buf) {
    const int k0 = tk * 32;
    unsigned short* Ah = Ahb3 + buf * 4096;
    unsigned short* Bs = Bsb3 + buf * 4096;
    gl_lds16(Ab + (size_t)srow * NXc + k0 + aco, &Ah[t * 8]);
    gl_lds16(Ab + (size_t)(srow + 64) * NXc + k0 + aco, &Ah[(256 + t) * 8]);
    gl_lds16(Bb + (size_t)srow * NXc + k0 + aco, &Bs[t * 8]);
    gl_lds16(Bb + (size_t)(srow + 64) * NXc + k0 + aco, &Bs[(256 + t) * 8]);
  };
  auto COMPUTE = [&](int buf) {
    const unsigned short* Ah = Ahb3 + buf * 4096;
    const unsigned short* Bs = Bsb3 + buf * 4096;
    half8 bfrag[4];
#pragma unroll
    for (int nf = 0; nf < 4; ++nf)
      bfrag[nf] = *(const half8*)&Bs[(wn * 64 + nf * 16 + ln) * 32 + rsw];
#pragma unroll
    for (int mf = 0; mf < 4; ++mf) {
      half8 ah = *(const half8*)&Ah[(wm * 64 + mf * 16 + ln) * 32 + rsw];
#pragma unroll
      for (int nf = 0; nf < 4; ++nf)
        acc[mf][nf] = __builtin_amdgcn_mfma_f32_16x16x32_f16(ah, bfrag[nf], acc[mf][nf], 0, 0, 0);
    }
  };

  STAGE(0, 0);
  STAGE(1, 1);
  for (int tk = 0; tk < 22; ++tk) {
    asm volatile("s_waitcnt vmcnt(4)" ::: "memory");
    __builtin_amdgcn_s_barrier();
    __builtin_amdgcn_sched_barrier(0);
    STAGE(tk + 2, (tk + 2) % 3);
    COMPUTE(tk % 3);
  }
  asm volatile("s_waitcnt vmcnt(4)" ::: "memory");
  __builtin_amdgcn_s_barrier();
  __builtin_amdgcn_sched_barrier(0);
  COMPUTE(22 % 3);
  asm volatile("s_waitcnt vmcnt(0)" ::: "memory");
  __builtin_amdgcn_s_barrier();
  __builtin_amdgcn_sched_barrier(0);
  COMPUTE(23 % 3);

  const float inv255 = 1.0f / 255.0f;
  if (EPI == 1 && part == 2) {
    __syncthreads();
#pragma unroll
    for (int mf = 0; mf < 4; ++mf) {
      int row0 = bm * 128 + wm * 64 + mf * 16 + g * 4;
#pragma unroll
      for (int nf = 0; nf < 4; ++nf) {
        int col = bn * 128 + wn * 64 + nf * 16 + ln;
        float bv = bias[col];
        int ff = col - 2 * NXc;
        int h = ff >> 6, d = ff & 63;
        int c = wn * 64 + nf * 16 + ln;
#pragma unroll
        for (int r = 0; r < 4; ++r) {
          float x = acc[mf][nf][r] * inv255 + bv;
          int row = row0 + r;
          int b = row >> 10, s = row & 1023;
          float y255 = rintf(fminf(fmaxf(x, 0.f), 1.f) * 255.0f);
          vq[(((size_t)b * H_ + h) * S_ + s) * HDc + d] = y255 * inv255;
          int sl = wm * 64 + mf * 16 + g * 4 + r;
          T[c * 136 + sl] = f2h(y255);
        }
      }
    }
    __syncthreads();
    const int bB = bm >> 3;
    const int s0 = (bm & 7) * 128;
    const int h0 = (bn - 12) * 2;
#pragma unroll
    for (int rep = 0; rep < 8; ++rep) {
      int idx = rep * 256 + t;
      int c = idx >> 4, sc = idx & 15;
      short8 v = *(const short8*)&T[c * 136 + sc * 8];
      int h = h0 + (c >> 6), d = c & 63;
      *(short8*)(vht + (((size_t)bB * H_ + h) * HDc + d) * S_ + s0 + sc * 8) = v;
    }
  } else {
#pragma unroll
    for (int mf = 0; mf < 4; ++mf) {
      int row0 = bm * 128 + wm * 64 + mf * 16 + g * 4;
#pragma unroll
      for (int nf = 0; nf < 4; ++nf) {
        int col = bn * 128 + wn * 64 + nf * 16 + ln;
        float bv = bias[col];
        int ff = col - part * NXc;
        int h = ff >> 6, d = ff & 63;
#pragma unroll
        for (int r = 0; r < 4; ++r) {
          float x = acc[mf][nf][r] * inv255 + bv;
          int row = row0 + r;
          if (EPI == 0) {
            Cout[(size_t)row * NXc + col] = x;
          } else {
            int b = row >> 10, s = row & 1023;
            float y255 = rintf(fminf(fmaxf(x, 0.f), 1.f) * 255.0f);
            unsigned short yh = f2h(y255);
            size_t dst = (((size_t)b * H_ + h) * S_ + s) * HDc + d;
            if (part == 0) {
              qh[dst] = yh;
            } else {
              kq[dst] = y255 * inv255;
              kh[dst] = yh;
            }
          }
        }
      }
    }
  }
}

// ---------------- MFMA causal flash attention (fp16, no-max softmax) ----------
// Scores s = q.k * SCALE are in [0, 8] EXACTLY (q,k quantized to [0,1]):
// exp(s) <= e^8 = 2981 fits fp16; l <= S*2981 fits fp32 -> max-subtraction is
// mathematically unnecessary. l accumulated per-lane, row-reduced ONCE at
// writeout. Head-chunked XCD swizzle: xcd = bid&7 owns 12 consecutive heads
// (Q+K+V ~4.5 MB, L2-resident).
__global__ __launch_bounds__(256) void k_attn_pair(
    const unsigned short* __restrict__ qh, const unsigned short* __restrict__ kh,
    const unsigned short* __restrict__ vht, unsigned short* __restrict__ ahf) {
  __shared__ __align__(16) unsigned short Ks[2][64 * 64];   // [kv][d]^((kv&7)<<3)
  __shared__ __align__(16) unsigned short Vt[2][64 * 64];   // [d][kv]^((d&7)<<3)
  __shared__ __align__(16) unsigned short Pp[4 * 16 * 64];  // per-wave P

  const int bid = blockIdx.x;                  // 768 = 8 xcd x 96
  const int gidx = (bid & 7) * 96 + (bid >> 3);
  const int hid = gidx >> 3;                   // head 0..95 (12 per XCD)
  const int p = gidx & 7;
  const int b = hid / H_, h = hid - b * H_;

  const size_t hoff = (size_t)hid * S_ * HDc;
  const unsigned short* qhp = qh + hoff;
  const unsigned short* khp = kh + hoff;
  const unsigned short* vhp = vht + hoff;

  const int t = threadIdx.x;
  const int w = t >> 6, lane = t & 63;
  const int g = lane >> 4, ln = lane & 15;

  const int r0 = t >> 3, c0 = (((t & 7) ^ (r0 & 7)) << 3);
  const int r1 = 32 + (t >> 3), c1 = (((t & 7) ^ (r1 & 7)) << 3);

  auto STAGE = [&](int jb, int buf) {
    gl_lds16(khp + (size_t)(jb * 64 + r0) * HDc + c0, &Ks[buf][t * 8]);
    gl_lds16(khp + (size_t)(jb * 64 + r1) * HDc + c1, &Ks[buf][(256 + t) * 8]);
    gl_lds16(vhp + (size_t)r0 * S_ + jb * 64 + c0, &Vt[buf][t * 8]);
    gl_lds16(vhp + (size_t)r1 * S_ + jb * 64 + c1, &Vt[buf][(256 + t) * 8]);
  };

  const float SCALE = 1.0f / (255.0f * 255.0f * 8.0f);

  int iq = p;
  half8 qfrag[2];
  {
    const unsigned short* qr = qhp + (size_t)(iq * 64 + w * 16 + ln) * HDc;
    qfrag[0] = *(const half8*)(qr + g * 8);
    qfrag[1] = *(const half8*)(qr + 32 + g * 8);
  }

  float l[4];
  f32x4 accO[4];
#pragma unroll
  for (int r = 0; r < 4; ++r) l[r] = 0.f;
#pragma unroll
  for (int nf = 0; nf < 4; ++nf) accO[nf] = (f32x4)(0.f);

  auto WRITEOUT = [&]() {
    // row-reduce l across the 16 ln-lanes (deferred from per-tile)
#pragma unroll
    for (int off = 1; off < 16; off <<= 1)
#pragma unroll
      for (int r = 0; r < 4; ++r) l[r] += __shfl_xor(l[r], off);
#pragma unroll
    for (int r = 0; r < 4; ++r) {
      float inv = 1.0f / (255.0f * l[r]);
      size_t row = (size_t)b * S_ + iq * 64 + w * 16 + g * 4 + r;
#pragma unroll
      for (int nf = 0; nf < 4; ++nf)
        ahf[row * NXc + h * HDc + nf * 16 + ln] = f2h(accO[nf][r] * inv);
    }
  };

  STAGE(0, 0);
  int jb = 0;
  for (int i = 0; i < 17; ++i) {
    const int buf = i & 1;
    __syncthreads();
    if (i + 1 < 17) {
      int njb = (i + 1 <= p) ? (i + 1) : (i - p);
      STAGE(njb, buf ^ 1);
    }

    // QK^T (exact integer)
    f32x4 accS[4];
#pragma unroll
    for (int nf = 0; nf < 4; ++nf) accS[nf] = (f32x4)(0.f);
#pragma unroll
    for (int ks = 0; ks < 2; ++ks)
#pragma unroll
      for (int nf = 0; nf < 4; ++nf) {
        int kvr = nf * 16 + ln;
        half8 bk = *(const half8*)&Ks[buf][kvr * 64 + ((ks * 32 + g * 8) ^ ((kvr & 7) << 3))];
        accS[nf] = __builtin_amdgcn_mfma_f32_16x16x32_f16(qfrag[ks], bk, accS[nf], 0, 0, 0);
      }

    // no-max softmax: p = exp(s), s in [0,8]; masked -> 0
    float pr[4][4];
    if (jb == iq) {
      const int grow = iq * 64 + w * 16 + g * 4;
      const int gcol = jb * 64 + ln;
#pragma unroll
      for (int nf = 0; nf < 4; ++nf)
#pragma unroll
        for (int r = 0; r < 4; ++r) {
          float pv = (gcol + nf * 16 > grow + r) ? 0.f : __expf(accS[nf][r] * SCALE);
          pr[nf][r] = pv;
          l[r] += pv;
        }
    } else {
#pragma unroll
      for (int nf = 0; nf < 4; ++nf)
#pragma unroll
        for (int r = 0; r < 4; ++r) {
          float pv = __expf(accS[nf][r] * SCALE);
          pr[nf][r] = pv;
          l[r] += pv;
        }
    }

    // P -> LDS (within-wave round trip)
#pragma unroll
    for (int nf = 0; nf < 4; ++nf)
#pragma unroll
      for (int r = 0; r < 4; ++r) {
        int prow = g * 4 + r;
        Pp[w * 1024 + prow * 64 + ((nf * 16 + ln) ^ ((prow & 7) << 3))] = f2h(pr[nf][r]);
      }

    // PV
#pragma unroll
    for (int ks = 0; ks < 2; ++ks) {
      half8 pa = *(const half8*)&Pp[w * 1024 + ln * 64 + ((ks * 32 + g * 8) ^ ((ln & 7) << 3))];
#pragma unroll
      for (int nf = 0; nf < 4; ++nf) {
        int d = nf * 16 + ln;
        half8 bv = *(const half8*)&Vt[buf][d * 64 + ((ks * 32 + g * 8) ^ ((d & 7) << 3))];
        accO[nf] = __builtin_amdgcn_mfma_f32_16x16x32_f16(pa, bv, accO[nf], 0, 0, 0);
      }
    }

    if (i == p) {
      WRITEOUT();
#pragma unroll
      for (int r = 0; r < 4; ++r) l[r] = 0.f;
#pragma unroll
      for (int nf = 0; nf < 4; ++nf) accO[nf] = (f32x4)(0.f);
      iq = 15 - p;
      const unsigned short* qr2 = qhp + (size_t)(iq * 64 + w * 16 + ln) * HDc;
      qfrag[0] = *(const half8*)(qr2 + g * 8);
      qfrag[1] = *(const half8*)(qr2 + 32 + g * 8);
    } else if (i == 16) {
      WRITEOUT();
    }
    jb = (i + 1 <= p) ? (i + 1) : (i - p);
  }
}

// ---------------- host launcher ----------------
extern "C" void kernel_launch(void* const* d_in, const int* in_sizes, int n_in,
                              void* d_out, int out_size, void* d_ws, size_t ws_size,
                              hipStream_t stream) {
  const float* x      = (const float*)d_in[0];
  const float* W_attn = (const float*)d_in[1];
  const float* b_attn = (const float*)d_in[2];
  const float* W_proj = (const float*)d_in[3];
  const float* b_proj = (const float*)d_in[4];

  float* out = (float*)d_out;
  float* ws  = (float*)d_ws;
  if (ws_size < WS_FLOATS_NEEDED * sizeof(float)) return;

  float* a_out = out;                               // [B,S,NX]
  float* k_out = out + (size_t)M_ * NXc;            // present[0] = k
  float* v_out = k_out + (size_t)M_ * NXc;          // present[1] = v

  unsigned short* ua  = (unsigned short*)(ws + UA_OFF_F);
  unsigned short* up  = (unsigned short*)(ws + UP_OFF_F);
  unsigned short* qh  = (unsigned short*)(ws + QH_OFF_F);
  unsigned short* kh  = (unsigned short*)(ws + KH_OFF_F);
  unsigned short* vht = (unsigned short*)(ws + VHT_OFF_F);
  unsigned short* ahf = (unsigned short*)(ws + AHF_OFF_F);
  unsigned int* sc = (unsigned int*)(ws + SC_OFF);

  unsigned short* xh = ahf;   // region reuse: attn writes ahf only after qkv read xh

  hipMemsetAsync(sc, 0, 2 * sizeof(unsigned int), stream);

  k_maxtanh2<<<dim3(128, 2), 256, 0, stream>>>(W_attn, W_proj, sc);

  k_quantw_t<<<dim3(NQKV / 64, NXc / 64), 256, 0, stream>>>(W_attn, ua, NXc, NQKV, sc);
  k_quantw_t<<<dim3(NXc / 64, NXc / 64), 256, 0, stream>>>(W_proj, up, NXc, NXc, sc + 1);

  k_xhalf<<<(M_ * NXc / 8 + 255) / 256, 256, 0, stream>>>(x, xh, M_ * NXc / 8);

  // qkv = x @ wq_attn + b_attn (fp16 MFMA, counted-vmcnt pipeline, LDS-transposed v)
  k_gemm3<1><<<(NQKV / 128) * (M_ / 128), 256, 0, stream>>>(
      xh, ua, b_attn, nullptr, qh, kh, vht, k_out, v_out, NQKV / 128);

  // causal attention (no-max softmax, head-chunked XCD swizzle)
  k_attn_pair<<<768, 256, 0, stream>>>(qh, kh, vht, ahf);

  // a = attn_out @ wq_proj + b_proj
  k_gemm3<0><<<(NXc / 128) * (M_ / 128), 256, 0, stream>>>(
      ahf, up, b_proj, a_out, nullptr, nullptr, nullptr, nullptr, nullptr, NXc / 128);
}